// Round 4
// baseline (154.821 us; speedup 1.0000x reference)
//
#include <hip/hip_runtime.h>
#include <hip/hip_bf16.h>
#include <stdint.h>

#define BB 2
#define SS 2048
#define DDIM 1024
#define HH 16
#define DEPTH 64
#define MROWS (BB*SS)   // 4096

typedef short bf16x8 __attribute__((ext_vector_type(8)));
typedef float f32x4 __attribute__((ext_vector_type(4)));

__device__ inline ushort f2bf(float f) {
  union { float f; unsigned u; } v; v.f = f;
  unsigned r = v.u + 0x7fffu + ((v.u >> 16) & 1u);
  return (ushort)(r >> 16);
}

__device__ inline void gload_lds16(const void* g, void* l) {
  __builtin_amdgcn_global_load_lds(
      (const __attribute__((address_space(1))) unsigned*)g,
      (__attribute__((address_space(3))) unsigned*)l,
      16, 0, 0);
}

// ---------------- fp32 -> bf16 convert (3 tensors fused) ----------------
__global__ void cvt3_kernel(const float* __restrict__ q, const float* __restrict__ k,
                            const float* __restrict__ v,
                            ushort* __restrict__ xq, ushort* __restrict__ xk,
                            ushort* __restrict__ xv, int n8) {
  int z = blockIdx.y;
  const float* in = (z == 0) ? q : (z == 1) ? k : v;
  ushort* out = (z == 0) ? xq : (z == 1) ? xk : xv;
  int i = blockIdx.x * blockDim.x + threadIdx.x;
  if (i >= n8) return;
  const float4* p = (const float4*)in + (size_t)i * 2;
  float4 a = p[0], b = p[1];
  ushort tmp[8] = { f2bf(a.x), f2bf(a.y), f2bf(a.z), f2bf(a.w),
                    f2bf(b.x), f2bf(b.y), f2bf(b.z), f2bf(b.w) };
  *(uint4*)(out + (size_t)i * 8) = *(uint4*)tmp;
}

// ---------------- weight transpose + convert: T[n][k] = W[k][n] ----------------
__global__ void wtrans_kernel(const float* __restrict__ W0, const float* __restrict__ W1,
                              const float* __restrict__ W2, const float* __restrict__ W3,
                              ushort* __restrict__ T0, ushort* __restrict__ T1,
                              ushort* __restrict__ T2, ushort* __restrict__ T3) {
  __shared__ float tile[32][33];
  int z = blockIdx.z;
  const float* W = (z == 0) ? W0 : (z == 1) ? W1 : (z == 2) ? W2 : W3;
  ushort* T = (z == 0) ? T0 : (z == 1) ? T1 : (z == 2) ? T2 : T3;
  int tx = threadIdx.x, ty = threadIdx.y;   // 32 x 8
  int n0 = blockIdx.x * 32, k0 = blockIdx.y * 32;
#pragma unroll
  for (int i = 0; i < 4; i++)
    tile[ty + i * 8][tx] = W[(size_t)(k0 + ty + i * 8) * DDIM + n0 + tx];
  __syncthreads();
#pragma unroll
  for (int i = 0; i < 4; i++)
    T[(size_t)(n0 + ty + i * 8) * DDIM + k0 + tx] = f2bf(tile[tx][ty + i * 8]);
}

// ---------------- fused Q/K/V projection GEMM (m97 structure, z selects) ----------
// out z=0: Qh[bh][2048][64], z=1: Kh[bh][2048][64], z=2: Vt[bh][64][2048]
__global__ __launch_bounds__(256) void qkv_gemm_kernel(
    const ushort* __restrict__ Xq, const ushort* __restrict__ Xk, const ushort* __restrict__ Xv,
    const ushort* __restrict__ Wqt, const ushort* __restrict__ Wkt, const ushort* __restrict__ Wvt,
    const float* __restrict__ bqp, const float* __restrict__ bkp, const float* __restrict__ bvp,
    ushort* __restrict__ Qh, ushort* __restrict__ Kh, ushort* __restrict__ Vtg) {
  const int z = blockIdx.z;
  const ushort* A  = (z == 0) ? Xq  : (z == 1) ? Xk  : Xv;
  const ushort* Bt = (z == 0) ? Wqt : (z == 1) ? Wkt : Wvt;
  const float* bias = (z == 0) ? bqp : (z == 1) ? bkp : bvp;
  const int K = DDIM;

  __shared__ __align__(16) ushort As[128 * 32];
  __shared__ __align__(16) ushort Bs[128 * 32];
  const int tid = threadIdx.x;
  const int w = tid >> 6, lane = tid & 63;
  const int m0 = blockIdx.y * 128, n0 = blockIdx.x * 128;
  const int wr = (w >> 1) * 64, wc = (w & 1) * 64;
  const int l4 = lane >> 4, l15 = lane & 15;
  const int srow = lane >> 2;
  const int scol = (lane & 3) * 8;

  f32x4 zero = {0.f, 0.f, 0.f, 0.f};
  f32x4 acc[4][4];
#pragma unroll
  for (int i = 0; i < 4; i++)
#pragma unroll
    for (int j = 0; j < 4; j++) acc[i][j] = zero;

  for (int k0 = 0; k0 < K; k0 += 32) {
#pragma unroll
    for (int it = 0; it < 2; ++it) {
      int r = it * 64 + w * 16;
      gload_lds16(A + (size_t)(m0 + r + srow) * K + k0 + scol, &As[r * 32]);
      gload_lds16(Bt + (size_t)(n0 + r + srow) * K + k0 + scol, &Bs[r * 32]);
    }
    __syncthreads();
    bf16x8 af[4], bfr[4];
#pragma unroll
    for (int m = 0; m < 4; m++)
      af[m] = *(const bf16x8*)&As[(wr + m * 16 + l15) * 32 + l4 * 8];
#pragma unroll
    for (int n = 0; n < 4; n++)
      bfr[n] = *(const bf16x8*)&Bs[(wc + n * 16 + l15) * 32 + l4 * 8];
#pragma unroll
    for (int m = 0; m < 4; m++)
#pragma unroll
      for (int n = 0; n < 4; n++)
        acc[m][n] = __builtin_amdgcn_mfma_f32_16x16x32_bf16(af[m], bfr[n], acc[m][n], 0, 0, 0);
    __syncthreads();
  }

  if (z != 2) {
    ushort* outp = (z == 0) ? Qh : Kh;
#pragma unroll
    for (int m = 0; m < 4; m++) {
#pragma unroll
      for (int n = 0; n < 4; n++) {
        int col = n0 + wc + n * 16 + l15;
        float bv = bias[col];
        int hh = col >> 6, dd = col & 63;
#pragma unroll
        for (int r = 0; r < 4; r++) {
          int row = m0 + wr + m * 16 + l4 * 4 + r;
          int bb = row >> 11, s = row & (SS - 1);
          outp[((size_t)(bb * HH + hh) * SS + s) * DEPTH + dd] = f2bf(acc[m][n][r] + bv);
        }
      }
    }
  } else {
    // V^T epilogue: per-wave LDS-bounce transpose -> coalesced 16B stores
    ushort* wtile = (w < 2) ? &As[w * 2048] : &Bs[(w - 2) * 2048];  // 32 d x 64 s
    const int gcol0 = n0 + wc;            // 64-aligned -> single head per wave
    const int hh = gcol0 >> 6;
    const int bb = m0 >> 11;
    const int s0g = (m0 + wr) & (SS - 1);
#pragma unroll
    for (int p = 0; p < 2; ++p) {
#pragma unroll
      for (int nn = 0; nn < 2; ++nn) {
        int n = p * 2 + nn;
        int dloc = nn * 16 + l15;         // 0..31
        float bv = bias[gcol0 + p * 32 + dloc];
#pragma unroll
        for (int m = 0; m < 4; m++) {
#pragma unroll
          for (int rr = 0; rr < 4; rr += 2) {
            int sloc = m * 16 + l4 * 4 + rr;
            int g = (sloc >> 3) ^ (dloc & 7);
            uint pk = (uint)f2bf(acc[m][n][rr] + bv) |
                      ((uint)f2bf(acc[m][n][rr + 1] + bv) << 16);
            *(uint*)&wtile[dloc * 64 + g * 8 + (sloc & 7)] = pk;
          }
        }
      }
      __syncthreads();
#pragma unroll
      for (int i = 0; i < 4; ++i) {
        int dloc = (lane >> 3) + i * 8;   // 0..31
        int gg = (lane & 7) ^ (dloc & 7);
        bf16x8 val = *(const bf16x8*)&wtile[dloc * 64 + gg * 8];
        int dglob = p * 32 + dloc;
        size_t addr = ((size_t)(bb * HH + hh) * DEPTH + dglob) * SS + s0g + (lane & 7) * 8;
        *(bf16x8*)&Vtg[addr] = val;
      }
      __syncthreads();
    }
  }
}

// ---------------- output GEMM: out = A[M][K] * Bt[N][K]^T + bias (f32 out) ------
__global__ __launch_bounds__(256) void out_gemm_kernel(
    const ushort* __restrict__ A, const ushort* __restrict__ Bt,
    const float* __restrict__ bias, float* __restrict__ out,
    int M, int N, int K) {
  __shared__ __align__(16) ushort As[128 * 32];
  __shared__ __align__(16) ushort Bs[128 * 32];
  const int tid = threadIdx.x;
  const int w = tid >> 6, lane = tid & 63;
  const int m0 = blockIdx.y * 128, n0 = blockIdx.x * 128;
  const int wr = (w >> 1) * 64, wc = (w & 1) * 64;
  const int l4 = lane >> 4, l15 = lane & 15;
  const int srow = lane >> 2;
  const int scol = (lane & 3) * 8;

  f32x4 zero = {0.f, 0.f, 0.f, 0.f};
  f32x4 acc[4][4];
#pragma unroll
  for (int i = 0; i < 4; i++)
#pragma unroll
    for (int j = 0; j < 4; j++) acc[i][j] = zero;

  for (int k0 = 0; k0 < K; k0 += 32) {
#pragma unroll
    for (int it = 0; it < 2; ++it) {
      int r = it * 64 + w * 16;
      gload_lds16(A + (size_t)(m0 + r + srow) * K + k0 + scol, &As[r * 32]);
      gload_lds16(Bt + (size_t)(n0 + r + srow) * K + k0 + scol, &Bs[r * 32]);
    }
    __syncthreads();
    bf16x8 af[4], bfr[4];
#pragma unroll
    for (int m = 0; m < 4; m++)
      af[m] = *(const bf16x8*)&As[(wr + m * 16 + l15) * 32 + l4 * 8];
#pragma unroll
    for (int n = 0; n < 4; n++)
      bfr[n] = *(const bf16x8*)&Bs[(wc + n * 16 + l15) * 32 + l4 * 8];
#pragma unroll
    for (int m = 0; m < 4; m++)
#pragma unroll
      for (int n = 0; n < 4; n++)
        acc[m][n] = __builtin_amdgcn_mfma_f32_16x16x32_bf16(af[m], bfr[n], acc[m][n], 0, 0, 0);
    __syncthreads();
  }

#pragma unroll
  for (int m = 0; m < 4; m++) {
#pragma unroll
    for (int n = 0; n < 4; n++) {
      int col = n0 + wc + n * 16 + l15;
      float bv = bias[col];
#pragma unroll
      for (int r = 0; r < 4; r++) {
        int row = m0 + wr + m * 16 + l4 * 4 + r;
        out[(size_t)row * N + col] = acc[m][n][r] + bv;
      }
    }
  }
}

// ---------------- causal flash attention: swapped-QK^T lane-local softmax --------
// Qh,Kh: [bh][2048][64] bf16 ; Vt: [bh][64][2048] bf16 ; ctx: [4096][1024] bf16
// Block = pair of q-chunks (c, 31-c), 64 rows each -> 33 tiles/block balanced.
__global__ __launch_bounds__(256) void attn_kernel(
    const ushort* __restrict__ Qh, const ushort* __restrict__ Kh,
    const ushort* __restrict__ Vt, ushort* __restrict__ ctx) {
  __shared__ __align__(16) ushort Ks[2][64 * 64];   // [kv][d], XOR-swizzled
  __shared__ __align__(16) ushort Vs[2][64 * 64];   // [d][kv], XOR-swizzled
  __shared__ __align__(16) ushort Ps[4][16 * 72];   // per-wave P^T, padded stride
  const int tid = threadIdx.x;
  const int w = tid >> 6, lane = tid & 63;
  const int l4 = lane >> 4, l15 = lane & 15;
  const float CE = 0.18033688f;                     // 0.125 * log2(e)

  int linear = blockIdx.x + blockIdx.y * 16;        // gridDim = (16, 32)
  int serial = (linear & 7) * 64 + (linear >> 3);   // bijective XCD swizzle
  const int qpair = serial & 15;
  const int bh = serial >> 4;
  const int b = bh >> 4, h = bh & 15;
  const size_t qkbase = (size_t)bh * SS * DEPTH;
  const size_t vbase  = (size_t)bh * DEPTH * SS;

  const int srow_w = w * 8 + (lane >> 3);
  const int colb_lin = (lane & 7) * 16;
  const int swz_rd = (l15 & 7) << 3;

  for (int pass = 0; pass < 2; ++pass) {
    const int chunk = pass ? (31 - qpair) : qpair;
    const int q0 = chunk * 64 + w * 16;
    const int nt = chunk + 1;

    bf16x8 aq[2];
#pragma unroll
    for (int cc = 0; cc < 2; cc++)
      aq[cc] = *(const bf16x8*)&Qh[qkbase + (size_t)(q0 + l15) * DEPTH + cc * 32 + l4 * 8];

    f32x4 zero = {0.f, 0.f, 0.f, 0.f};
    f32x4 o[4];
    float m_run = -__builtin_inff(), l_run = 0.f;
#pragma unroll
    for (int d = 0; d < 4; d++) o[d] = zero;

    int buf = 0;
#pragma unroll
    for (int it = 0; it < 2; ++it) {
      int row = it * 32 + srow_w;
      int col_e = (colb_lin ^ ((row & 7) << 4)) >> 1;
      int ldsoff = it * 2048 + w * 512;
      gload_lds16(Kh + qkbase + (size_t)row * DEPTH + col_e, &Ks[0][ldsoff]);
      gload_lds16(Vt + vbase + (size_t)row * SS + col_e, &Vs[0][ldsoff]);
    }
    __syncthreads();

    for (int t = 0; t < nt; ++t) {
      if (t + 1 < nt) {
        const int kv1 = (t + 1) * 64;
#pragma unroll
        for (int it = 0; it < 2; ++it) {
          int row = it * 32 + srow_w;
          int col_e = (colb_lin ^ ((row & 7) << 4)) >> 1;
          int ldsoff = it * 2048 + w * 512;
          gload_lds16(Kh + qkbase + (size_t)(kv1 + row) * DEPTH + col_e, &Ks[buf ^ 1][ldsoff]);
          gload_lds16(Vt + vbase + (size_t)row * SS + kv1 + col_e, &Vs[buf ^ 1][ldsoff]);
        }
      }

      const int kv0 = t * 64;
      // ---- S^T = K Q^T (swapped operands): lane holds 16 k's of q = q0+l15 ----
      f32x4 s[4];
      __builtin_amdgcn_s_setprio(1);
#pragma unroll
      for (int n = 0; n < 4; n++) {
        f32x4 zacc = zero;
        int kr = n * 16 + l15;
#pragma unroll
        for (int cc = 0; cc < 2; cc++) {
          bf16x8 bk = *(const bf16x8*)&Ks[buf][kr * 64 + ((cc * 32 + l4 * 8) ^ swz_rd)];
          zacc = __builtin_amdgcn_mfma_f32_16x16x32_bf16(bk, aq[cc], zacc, 0, 0, 0);
        }
        s[n] = zacc;
      }
      __builtin_amdgcn_s_setprio(0);

      const int qg = q0 + l15;
      if (t == nt - 1) {
#pragma unroll
        for (int n = 0; n < 4; n++) {
          int kb = kv0 + n * 16 + l4 * 4;
#pragma unroll
          for (int r = 0; r < 4; r++)
            if (kb + r > qg) s[n][r] = -1e9f;
        }
      }

      // ---- lane-local online softmax (raw units; exp2 with folded scale) ----
      float mx = -__builtin_inff();
#pragma unroll
      for (int n = 0; n < 4; n++)
        mx = fmaxf(mx, fmaxf(fmaxf(s[n][0], s[n][1]), fmaxf(s[n][2], s[n][3])));
      mx = fmaxf(mx, __shfl_xor(mx, 16));
      mx = fmaxf(mx, __shfl_xor(mx, 32));
      if (!__all(mx - m_run <= 44.36f)) {      // defer-max: P bounded by 2^8
        float mnew = fmaxf(m_run, mx);
        float alpha = exp2f((m_run - mnew) * CE);
        m_run = mnew;
        l_run *= alpha;
#pragma unroll
        for (int d = 0; d < 4; d++) o[d] *= alpha;
      }
      float mc = m_run * CE;
      float rs = 0.f;
#pragma unroll
      for (int n = 0; n < 4; n++)
#pragma unroll
        for (int r = 0; r < 4; r++) {
          float p = exp2f(s[n][r] * CE - mc);
          s[n][r] = p;
          rs += p;
        }
      l_run += rs;

      // ---- P^T -> wave-private LDS (packed pair writes) ----
      ushort* Pw = &Ps[w][0];
#pragma unroll
      for (int n = 0; n < 4; n++) {
        uint lo = (uint)f2bf(s[n][0]) | ((uint)f2bf(s[n][1]) << 16);
        uint hi = (uint)f2bf(s[n][2]) | ((uint)f2bf(s[n][3]) << 16);
        *(uint*)&Pw[l15 * 72 + n * 16 + l4 * 4]     = lo;
        *(uint*)&Pw[l15 * 72 + n * 16 + l4 * 4 + 2] = hi;
      }

      bf16x8 pa[2];
#pragma unroll
      for (int cc = 0; cc < 2; cc++)
        pa[cc] = *(const bf16x8*)&Pw[l15 * 72 + cc * 32 + l4 * 8];

      // ---- O^T += V^T P^T (swapped): lane accumulates col q = l15 ----
      __builtin_amdgcn_s_setprio(1);
#pragma unroll
      for (int d = 0; d < 4; d++) {
        int dr = d * 16 + l15;
#pragma unroll
        for (int cc = 0; cc < 2; cc++) {
          bf16x8 av = *(const bf16x8*)&Vs[buf][dr * 64 + ((cc * 32 + l4 * 8) ^ swz_rd)];
          o[d] = __builtin_amdgcn_mfma_f32_16x16x32_bf16(av, pa[cc], o[d], 0, 0, 0);
        }
      }
      __builtin_amdgcn_s_setprio(0);

      __syncthreads();
      buf ^= 1;
    }

    // ---- finalize: cross-l4 sum of l_run, normalize, packed ctx write ----
    float lv = l_run;
    lv += __shfl_xor(lv, 16);
    lv += __shfl_xor(lv, 32);
    float inv = 1.f / lv;
    size_t rowbase = ((size_t)(b * SS + q0 + l15)) * DDIM + h * DEPTH;
#pragma unroll
    for (int d = 0; d < 4; d++) {
      uint lo = (uint)f2bf(o[d][0] * inv) | ((uint)f2bf(o[d][1] * inv) << 16);
      uint hi = (uint)f2bf(o[d][2] * inv) | ((uint)f2bf(o[d][3] * inv) << 16);
      *(uint*)&ctx[rowbase + d * 16 + l4 * 4]     = lo;
      *(uint*)&ctx[rowbase + d * 16 + l4 * 4 + 2] = hi;
    }
  }
}

extern "C" void kernel_launch(void* const* d_in, const int* in_sizes, int n_in,
                              void* d_out, int out_size, void* d_ws, size_t ws_size,
                              hipStream_t stream) {
  const float* query = (const float*)d_in[0];
  const float* key_  = (const float*)d_in[1];
  const float* value = (const float*)d_in[2];
  const float* Wq = (const float*)d_in[4];
  const float* Wk = (const float*)d_in[5];
  const float* Wv = (const float*)d_in[6];
  const float* Wo = (const float*)d_in[7];
  const float* bq = (const float*)d_in[8];
  const float* bk = (const float*)d_in[9];
  const float* bv = (const float*)d_in[10];
  const float* bo = (const float*)d_in[11];

  char* ws = (char*)d_ws;
  const size_t MB = 1u << 20;
  ushort* Xq  = (ushort*)(ws + 0 * MB);
  ushort* Xk  = (ushort*)(ws + 8 * MB);
  ushort* Xv  = (ushort*)(ws + 16 * MB);
  ushort* Wqt = (ushort*)(ws + 24 * MB);
  ushort* Wkt = (ushort*)(ws + 26 * MB);
  ushort* Wvt = (ushort*)(ws + 28 * MB);
  ushort* Wot = (ushort*)(ws + 30 * MB);
  ushort* Qh  = (ushort*)(ws + 32 * MB);   // [bh][2048][64]
  ushort* Kh  = (ushort*)(ws + 40 * MB);   // [bh][2048][64]
  ushort* Vtg = (ushort*)(ws + 48 * MB);   // [bh][64][2048]
  ushort* Cb  = (ushort*)(ws + 56 * MB);   // [4096][1024]

  const int n = MROWS * DDIM;
  const int n8 = n / 8;
  cvt3_kernel<<<dim3(n8 / 256, 3), 256, 0, stream>>>(query, key_, value, Xq, Xk, Xv, n8);
  wtrans_kernel<<<dim3(32, 32, 4), dim3(32, 8), 0, stream>>>(
      Wq, Wk, Wv, Wo, Wqt, Wkt, Wvt, Wot);

  qkv_gemm_kernel<<<dim3(DDIM / 128, MROWS / 128, 3), 256, 0, stream>>>(
      Xq, Xk, Xv, Wqt, Wkt, Wvt, bq, bk, bv, Qh, Kh, Vtg);

  attn_kernel<<<dim3(16, 32), 256, 0, stream>>>(Qh, Kh, Vtg, Cb);

  out_gemm_kernel<<<dim3(DDIM / 128, MROWS / 128), 256, 0, stream>>>(
      Cb, Wot, bo, (float*)d_out, MROWS, DDIM, DDIM);
}

// Round 5
// 134.740 us; speedup vs baseline: 1.1490x; 1.1490x over previous
//
#include <hip/hip_runtime.h>
#include <hip/hip_bf16.h>
#include <stdint.h>

#define BB 2
#define SS 2048
#define DDIM 1024
#define HH 16
#define DEPTH 64
#define MROWS (BB*SS)   // 4096

typedef short bf16x8 __attribute__((ext_vector_type(8)));
typedef float f32x4 __attribute__((ext_vector_type(4)));

__device__ inline ushort f2bf(float f) {
  union { float f; unsigned u; } v; v.f = f;
  unsigned r = v.u + 0x7fffu + ((v.u >> 16) & 1u);
  return (ushort)(r >> 16);
}

// HW packed f32x2 -> bf16x2 (RTNE), low = a, high = b  [m214 T12]
__device__ inline uint pkbf(float a, float b) {
  uint r;
  asm("v_cvt_pk_bf16_f32 %0, %1, %2" : "=v"(r) : "v"(a), "v"(b));
  return r;
}

__device__ inline void gload_lds16(const void* g, void* l) {
  __builtin_amdgcn_global_load_lds(
      (const __attribute__((address_space(1))) unsigned*)g,
      (__attribute__((address_space(3))) unsigned*)l,
      16, 0, 0);
}

// ---------------- prep: fused fp32->bf16 convert (3 tensors) + 4 weight transposes
__global__ void prep_kernel(const float* __restrict__ q, const float* __restrict__ k,
                            const float* __restrict__ v,
                            ushort* __restrict__ xq, ushort* __restrict__ xk,
                            ushort* __restrict__ xv,
                            const float* __restrict__ W0, const float* __restrict__ W1,
                            const float* __restrict__ W2, const float* __restrict__ W3,
                            ushort* __restrict__ T0, ushort* __restrict__ T1,
                            ushort* __restrict__ T2, ushort* __restrict__ T3) {
  __shared__ float tile[32][33];
  if (blockIdx.x < 6144) {
    int z = blockIdx.x >> 11;                       // 2048 blocks per tensor
    const float* in = (z == 0) ? q : (z == 1) ? k : v;
    ushort* out = (z == 0) ? xq : (z == 1) ? xk : xv;
    int i = (blockIdx.x & 2047) * 256 + threadIdx.x;
    const float4* p = (const float4*)in + (size_t)i * 2;
    float4 a = p[0], b = p[1];
    uint tmp[4] = { pkbf(a.x, a.y), pkbf(a.z, a.w), pkbf(b.x, b.y), pkbf(b.z, b.w) };
    *(uint4*)(out + (size_t)i * 8) = *(uint4*)tmp;
  } else {
    int idx = blockIdx.x - 6144;
    int z = idx >> 10;
    int rr = idx & 1023;
    const float* W = (z == 0) ? W0 : (z == 1) ? W1 : (z == 2) ? W2 : W3;
    ushort* T = (z == 0) ? T0 : (z == 1) ? T1 : (z == 2) ? T2 : T3;
    int tx = threadIdx.x & 31, ty = threadIdx.x >> 5;   // 32 x 8
    int n0 = (rr & 31) * 32, k0 = (rr >> 5) * 32;
#pragma unroll
    for (int i = 0; i < 4; i++)
      tile[ty + i * 8][tx] = W[(size_t)(k0 + ty + i * 8) * DDIM + n0 + tx];
    __syncthreads();
#pragma unroll
    for (int i = 0; i < 4; i++)
      T[(size_t)(n0 + ty + i * 8) * DDIM + k0 + tx] = f2bf(tile[tx][ty + i * 8]);
  }
}

// ---------------- fused Q/K/V projection GEMM (m97 structure, z selects) ----------
// out z=0: Qh[bh][2048][64], z=1: Kh[bh][2048][64], z=2: Vt[bh][64][2048]
__global__ __launch_bounds__(256) void qkv_gemm_kernel(
    const ushort* __restrict__ Xq, const ushort* __restrict__ Xk, const ushort* __restrict__ Xv,
    const ushort* __restrict__ Wqt, const ushort* __restrict__ Wkt, const ushort* __restrict__ Wvt,
    const float* __restrict__ bqp, const float* __restrict__ bkp, const float* __restrict__ bvp,
    ushort* __restrict__ Qh, ushort* __restrict__ Kh, ushort* __restrict__ Vtg) {
  const int z = blockIdx.z;
  const ushort* A  = (z == 0) ? Xq  : (z == 1) ? Xk  : Xv;
  const ushort* Bt = (z == 0) ? Wqt : (z == 1) ? Wkt : Wvt;
  const float* bias = (z == 0) ? bqp : (z == 1) ? bkp : bvp;
  const int K = DDIM;

  __shared__ __align__(16) ushort As[128 * 32];
  __shared__ __align__(16) ushort Bs[128 * 32];
  const int tid = threadIdx.x;
  const int w = tid >> 6, lane = tid & 63;
  const int m0 = blockIdx.y * 128, n0 = blockIdx.x * 128;
  const int wr = (w >> 1) * 64, wc = (w & 1) * 64;
  const int l4 = lane >> 4, l15 = lane & 15;
  const int srow = lane >> 2;
  const int scol = (lane & 3) * 8;

  f32x4 zero = {0.f, 0.f, 0.f, 0.f};
  f32x4 acc[4][4];
#pragma unroll
  for (int i = 0; i < 4; i++)
#pragma unroll
    for (int j = 0; j < 4; j++) acc[i][j] = zero;

  for (int k0 = 0; k0 < K; k0 += 32) {
#pragma unroll
    for (int it = 0; it < 2; ++it) {
      int r = it * 64 + w * 16;
      gload_lds16(A + (size_t)(m0 + r + srow) * K + k0 + scol, &As[r * 32]);
      gload_lds16(Bt + (size_t)(n0 + r + srow) * K + k0 + scol, &Bs[r * 32]);
    }
    __syncthreads();
    bf16x8 af[4], bfr[4];
#pragma unroll
    for (int m = 0; m < 4; m++)
      af[m] = *(const bf16x8*)&As[(wr + m * 16 + l15) * 32 + l4 * 8];
#pragma unroll
    for (int n = 0; n < 4; n++)
      bfr[n] = *(const bf16x8*)&Bs[(wc + n * 16 + l15) * 32 + l4 * 8];
#pragma unroll
    for (int m = 0; m < 4; m++)
#pragma unroll
      for (int n = 0; n < 4; n++)
        acc[m][n] = __builtin_amdgcn_mfma_f32_16x16x32_bf16(af[m], bfr[n], acc[m][n], 0, 0, 0);
    __syncthreads();
  }

  if (z != 2) {
    ushort* outp = (z == 0) ? Qh : Kh;
#pragma unroll
    for (int m = 0; m < 4; m++) {
#pragma unroll
      for (int n = 0; n < 4; n++) {
        int col = n0 + wc + n * 16 + l15;
        float bv = bias[col];
        int hh = col >> 6, dd = col & 63;
#pragma unroll
        for (int r = 0; r < 4; r++) {
          int row = m0 + wr + m * 16 + l4 * 4 + r;
          int bb = row >> 11, s = row & (SS - 1);
          outp[((size_t)(bb * HH + hh) * SS + s) * DEPTH + dd] = f2bf(acc[m][n][r] + bv);
        }
      }
    }
  } else {
    // V^T epilogue: per-wave LDS-bounce transpose -> coalesced 16B stores
    ushort* wtile = (w < 2) ? &As[w * 2048] : &Bs[(w - 2) * 2048];  // 32 d x 64 s
    const int gcol0 = n0 + wc;
    const int hh = gcol0 >> 6;
    const int bb = m0 >> 11;
    const int s0g = (m0 + wr) & (SS - 1);
#pragma unroll
    for (int p = 0; p < 2; ++p) {
#pragma unroll
      for (int nn = 0; nn < 2; ++nn) {
        int n = p * 2 + nn;
        int dloc = nn * 16 + l15;
        float bv = bias[gcol0 + p * 32 + dloc];
#pragma unroll
        for (int m = 0; m < 4; m++) {
#pragma unroll
          for (int rr = 0; rr < 4; rr += 2) {
            int sloc = m * 16 + l4 * 4 + rr;
            int g = (sloc >> 3) ^ (dloc & 7);
            uint pk = pkbf(acc[m][n][rr] + bv, acc[m][n][rr + 1] + bv);
            *(uint*)&wtile[dloc * 64 + g * 8 + (sloc & 7)] = pk;
          }
        }
      }
      __syncthreads();
#pragma unroll
      for (int i = 0; i < 4; ++i) {
        int dloc = (lane >> 3) + i * 8;
        int gg = (lane & 7) ^ (dloc & 7);
        bf16x8 val = *(const bf16x8*)&wtile[dloc * 64 + gg * 8];
        int dglob = p * 32 + dloc;
        size_t addr = ((size_t)(bb * HH + hh) * DEPTH + dglob) * SS + s0g + (lane & 7) * 8;
        *(bf16x8*)&Vtg[addr] = val;
      }
      __syncthreads();
    }
  }
}

// ---------------- output GEMM: 128x64 tile (512 blocks -> 2 blocks/CU) ----------
__global__ __launch_bounds__(256, 2) void out_gemm_kernel(
    const ushort* __restrict__ A, const ushort* __restrict__ Bt,
    const float* __restrict__ bias, float* __restrict__ out,
    int M, int N, int K) {
  __shared__ __align__(16) ushort As[128 * 32];
  __shared__ __align__(16) ushort Bs[64 * 32];
  const int tid = threadIdx.x;
  const int w = tid >> 6, lane = tid & 63;
  const int m0 = blockIdx.y * 128, n0 = blockIdx.x * 64;
  const int wr = (w >> 1) * 64, wc = (w & 1) * 32;
  const int l4 = lane >> 4, l15 = lane & 15;
  const int srow = lane >> 2;
  const int scol = (lane & 3) * 8;

  f32x4 zero = {0.f, 0.f, 0.f, 0.f};
  f32x4 acc[4][2];
#pragma unroll
  for (int i = 0; i < 4; i++)
#pragma unroll
    for (int j = 0; j < 2; j++) acc[i][j] = zero;

  for (int k0 = 0; k0 < K; k0 += 32) {
#pragma unroll
    for (int it = 0; it < 2; ++it) {
      int r = it * 64 + w * 16;
      gload_lds16(A + (size_t)(m0 + r + srow) * K + k0 + scol, &As[r * 32]);
    }
    gload_lds16(Bt + (size_t)(n0 + w * 16 + srow) * K + k0 + scol, &Bs[(w * 16) * 32]);
    __syncthreads();
    bf16x8 af[4], bfr[2];
#pragma unroll
    for (int m = 0; m < 4; m++)
      af[m] = *(const bf16x8*)&As[(wr + m * 16 + l15) * 32 + l4 * 8];
#pragma unroll
    for (int n = 0; n < 2; n++)
      bfr[n] = *(const bf16x8*)&Bs[(wc + n * 16 + l15) * 32 + l4 * 8];
#pragma unroll
    for (int m = 0; m < 4; m++)
#pragma unroll
      for (int n = 0; n < 2; n++)
        acc[m][n] = __builtin_amdgcn_mfma_f32_16x16x32_bf16(af[m], bfr[n], acc[m][n], 0, 0, 0);
    __syncthreads();
  }

#pragma unroll
  for (int m = 0; m < 4; m++) {
#pragma unroll
    for (int n = 0; n < 2; n++) {
      int col = n0 + wc + n * 16 + l15;
      float bv = bias[col];
#pragma unroll
      for (int r = 0; r < 4; r++) {
        int row = m0 + wr + m * 16 + l4 * 4 + r;
        out[(size_t)row * N + col] = acc[m][n][r] + bv;
      }
    }
  }
}

// ---------------- causal flash attention: 1024 LPT-ordered blocks, 4/CU ---------
// Qh,Kh: [bh][2048][64] bf16 ; Vt: [bh][64][2048] bf16 ; ctx: [4096][1024] bf16
__global__ __launch_bounds__(256, 4) void attn_kernel(
    const ushort* __restrict__ Qh, const ushort* __restrict__ Kh,
    const ushort* __restrict__ Vt, ushort* __restrict__ ctx) {
  __shared__ __align__(16) ushort Ks[2][64 * 64];   // [kv][d], XOR-swizzled
  __shared__ __align__(16) ushort Vs[2][64 * 64];   // [d][kv], XOR-swizzled
  __shared__ __align__(16) ushort Ps[4][16 * 64];   // per-wave P, XOR-swizzled
  const int tid = threadIdx.x;
  const int w = tid >> 6, lane = tid & 63;
  const int l4 = lane >> 4, l15 = lane & 15;
  const float CE = 0.18033688f;                     // 0.125 * log2(e)

  // LPT + XCD: xcd owns 4 heads; within xcd, big chunks dispatched first
  const int xcd = blockIdx.x & 7;
  const int local = blockIdx.x >> 3;                // 0..127
  const int bh = xcd * 4 + (local & 3);
  const int chunk = 31 - (local >> 2);
  const int b = bh >> 4, h = bh & 15;
  const size_t qkbase = (size_t)bh * SS * DEPTH;
  const size_t vbase  = (size_t)bh * DEPTH * SS;

  const int srow_w = w * 8 + (lane >> 3);
  const int colb_lin = (lane & 7) * 16;
  const int swz_rd = (l15 & 7) << 3;                // element XOR (K/V and Ps reads)

  const int q0 = chunk * 64 + w * 16;
  const int nt = chunk + 1;

  bf16x8 aq[2];
#pragma unroll
  for (int cc = 0; cc < 2; cc++)
    aq[cc] = *(const bf16x8*)&Qh[qkbase + (size_t)(q0 + l15) * DEPTH + cc * 32 + l4 * 8];

  f32x4 zero = {0.f, 0.f, 0.f, 0.f};
  f32x4 o[4];
  float m_run = -__builtin_inff(), l_run = 0.f;
#pragma unroll
  for (int d = 0; d < 4; d++) o[d] = zero;

  int buf = 0;
#pragma unroll
  for (int it = 0; it < 2; ++it) {
    int row = it * 32 + srow_w;
    int col_e = (colb_lin ^ ((row & 7) << 4)) >> 1;
    int ldsoff = it * 2048 + w * 512;
    gload_lds16(Kh + qkbase + (size_t)row * DEPTH + col_e, &Ks[0][ldsoff]);
    gload_lds16(Vt + vbase + (size_t)row * SS + col_e, &Vs[0][ldsoff]);
  }
  __syncthreads();

  for (int t = 0; t < nt; ++t) {
    if (t + 1 < nt) {
      const int kv1 = (t + 1) * 64;
#pragma unroll
      for (int it = 0; it < 2; ++it) {
        int row = it * 32 + srow_w;
        int col_e = (colb_lin ^ ((row & 7) << 4)) >> 1;
        int ldsoff = it * 2048 + w * 512;
        gload_lds16(Kh + qkbase + (size_t)(kv1 + row) * DEPTH + col_e, &Ks[buf ^ 1][ldsoff]);
        gload_lds16(Vt + vbase + (size_t)row * SS + kv1 + col_e, &Vs[buf ^ 1][ldsoff]);
      }
    }

    const int kv0 = t * 64;
    // ---- S^T = K Q^T (swapped): lane holds 16 k's of q = q0 + l15 ----
    f32x4 s[4];
    __builtin_amdgcn_s_setprio(1);
#pragma unroll
    for (int n = 0; n < 4; n++) {
      f32x4 zacc = zero;
      int kr = n * 16 + l15;
#pragma unroll
      for (int cc = 0; cc < 2; cc++) {
        bf16x8 bk = *(const bf16x8*)&Ks[buf][kr * 64 + ((cc * 32 + l4 * 8) ^ swz_rd)];
        zacc = __builtin_amdgcn_mfma_f32_16x16x32_bf16(bk, aq[cc], zacc, 0, 0, 0);
      }
      s[n] = zacc;
    }
    __builtin_amdgcn_s_setprio(0);

    const int qg = q0 + l15;
    if (t == nt - 1) {
#pragma unroll
      for (int n = 0; n < 4; n++) {
        int kb = kv0 + n * 16 + l4 * 4;
#pragma unroll
        for (int r = 0; r < 4; r++)
          if (kb + r > qg) s[n][r] = -1e9f;
      }
    }

    // ---- lane-local online softmax (raw units; exp2 with folded scale) ----
    float mx = -__builtin_inff();
#pragma unroll
    for (int n = 0; n < 4; n++)
      mx = fmaxf(mx, fmaxf(fmaxf(s[n][0], s[n][1]), fmaxf(s[n][2], s[n][3])));
    mx = fmaxf(mx, __shfl_xor(mx, 16));
    mx = fmaxf(mx, __shfl_xor(mx, 32));
    if (!__all(mx - m_run <= 44.36f)) {      // defer-max: P bounded by 2^8
      float mnew = fmaxf(m_run, mx);
      float alpha = exp2f((m_run - mnew) * CE);
      m_run = mnew;
      l_run *= alpha;
#pragma unroll
      for (int d = 0; d < 4; d++) o[d] *= alpha;
    }
    float mc = m_run * CE;
    float rs = 0.f;
#pragma unroll
    for (int n = 0; n < 4; n++)
#pragma unroll
      for (int r = 0; r < 4; r++) {
        float p = exp2f(s[n][r] * CE - mc);
        s[n][r] = p;
        rs += p;
      }
    l_run += rs;

    // ---- P -> wave-private swizzled LDS (HW cvt_pk packed writes) ----
    ushort* Pw = &Ps[w][0];
#pragma unroll
    for (int n = 0; n < 4; n++) {
      int col = (n * 16 + l4 * 4) ^ swz_rd;
      *(uint*)&Pw[l15 * 64 + col]     = pkbf(s[n][0], s[n][1]);
      *(uint*)&Pw[l15 * 64 + col + 2] = pkbf(s[n][2], s[n][3]);
    }

    bf16x8 pa[2];
#pragma unroll
    for (int cc = 0; cc < 2; cc++)
      pa[cc] = *(const bf16x8*)&Pw[l15 * 64 + ((cc * 32 + l4 * 8) ^ swz_rd)];

    // ---- O^T += V^T P^T (swapped): lane accumulates col q = l15 ----
    __builtin_amdgcn_s_setprio(1);
#pragma unroll
    for (int d = 0; d < 4; d++) {
      int dr = d * 16 + l15;
#pragma unroll
      for (int cc = 0; cc < 2; cc++) {
        bf16x8 av = *(const bf16x8*)&Vs[buf][dr * 64 + ((cc * 32 + l4 * 8) ^ swz_rd)];
        o[d] = __builtin_amdgcn_mfma_f32_16x16x32_bf16(av, pa[cc], o[d], 0, 0, 0);
      }
    }
    __builtin_amdgcn_s_setprio(0);

    __syncthreads();
    buf ^= 1;
  }

  // ---- finalize: cross-half sum of l_run, normalize, packed ctx write ----
  float lv = l_run;
  lv += __shfl_xor(lv, 16);
  lv += __shfl_xor(lv, 32);
  float inv = 1.f / lv;
  size_t rowbase = ((size_t)(b * SS + q0 + l15)) * DDIM + h * DEPTH;
#pragma unroll
  for (int d = 0; d < 4; d++) {
    *(uint*)&ctx[rowbase + d * 16 + l4 * 4]     = pkbf(o[d][0] * inv, o[d][1] * inv);
    *(uint*)&ctx[rowbase + d * 16 + l4 * 4 + 2] = pkbf(o[d][2] * inv, o[d][3] * inv);
  }
}

extern "C" void kernel_launch(void* const* d_in, const int* in_sizes, int n_in,
                              void* d_out, int out_size, void* d_ws, size_t ws_size,
                              hipStream_t stream) {
  const float* query = (const float*)d_in[0];
  const float* key_  = (const float*)d_in[1];
  const float* value = (const float*)d_in[2];
  const float* Wq = (const float*)d_in[4];
  const float* Wk = (const float*)d_in[5];
  const float* Wv = (const float*)d_in[6];
  const float* Wo = (const float*)d_in[7];
  const float* bq = (const float*)d_in[8];
  const float* bk = (const float*)d_in[9];
  const float* bv = (const float*)d_in[10];
  const float* bo = (const float*)d_in[11];

  char* ws = (char*)d_ws;
  const size_t MB = 1u << 20;
  ushort* Xq  = (ushort*)(ws + 0 * MB);
  ushort* Xk  = (ushort*)(ws + 8 * MB);
  ushort* Xv  = (ushort*)(ws + 16 * MB);
  ushort* Wqt = (ushort*)(ws + 24 * MB);
  ushort* Wkt = (ushort*)(ws + 26 * MB);
  ushort* Wvt = (ushort*)(ws + 28 * MB);
  ushort* Wot = (ushort*)(ws + 30 * MB);
  ushort* Qh  = (ushort*)(ws + 32 * MB);   // [bh][2048][64]
  ushort* Kh  = (ushort*)(ws + 40 * MB);   // [bh][2048][64]
  ushort* Vtg = (ushort*)(ws + 48 * MB);   // [bh][64][2048]
  ushort* Cb  = (ushort*)(ws + 56 * MB);   // [4096][1024]

  prep_kernel<<<6144 + 4096, 256, 0, stream>>>(query, key_, value, Xq, Xk, Xv,
                                               Wq, Wk, Wv, Wo, Wqt, Wkt, Wvt, Wot);

  qkv_gemm_kernel<<<dim3(DDIM / 128, MROWS / 128, 3), 256, 0, stream>>>(
      Xq, Xk, Xv, Wqt, Wkt, Wvt, bq, bk, bv, Qh, Kh, Vtg);

  attn_kernel<<<1024, 256, 0, stream>>>(Qh, Kh, Vtg, Cb);

  out_gemm_kernel<<<dim3(DDIM / 64, MROWS / 128), 256, 0, stream>>>(
      Cb, Wot, bo, (float*)d_out, MROWS, DDIM, DDIM);
}

// Round 6
// 128.133 us; speedup vs baseline: 1.2083x; 1.0516x over previous
//
#include <hip/hip_runtime.h>
#include <hip/hip_bf16.h>
#include <stdint.h>

#define BB 2
#define SS 2048
#define DDIM 1024
#define HH 16
#define DEPTH 64
#define MROWS (BB*SS)   // 4096

typedef short bf16x8 __attribute__((ext_vector_type(8)));
typedef float f32x4 __attribute__((ext_vector_type(4)));

__device__ inline ushort f2bf(float f) {
  union { float f; unsigned u; } v; v.f = f;
  unsigned r = v.u + 0x7fffu + ((v.u >> 16) & 1u);
  return (ushort)(r >> 16);
}

// HW packed f32x2 -> bf16x2 (RTNE), low = a, high = b  [m214 T12]
__device__ inline uint pkbf(float a, float b) {
  uint r;
  asm("v_cvt_pk_bf16_f32 %0, %1, %2" : "=v"(r) : "v"(a), "v"(b));
  return r;
}

__device__ inline void gload_lds16(const void* g, void* l) {
  __builtin_amdgcn_global_load_lds(
      (const __attribute__((address_space(1))) unsigned*)g,
      (__attribute__((address_space(3))) unsigned*)l,
      16, 0, 0);
}

// ---------------- prep: fused fp32->bf16 convert (3 tensors) + 4 weight transposes
__global__ void prep_kernel(const float* __restrict__ q, const float* __restrict__ k,
                            const float* __restrict__ v,
                            ushort* __restrict__ xq, ushort* __restrict__ xk,
                            ushort* __restrict__ xv,
                            const float* __restrict__ W0, const float* __restrict__ W1,
                            const float* __restrict__ W2, const float* __restrict__ W3,
                            ushort* __restrict__ T0, ushort* __restrict__ T1,
                            ushort* __restrict__ T2, ushort* __restrict__ T3) {
  __shared__ float tile[32][33];
  if (blockIdx.x < 6144) {
    int z = blockIdx.x >> 11;                       // 2048 blocks per tensor
    const float* in = (z == 0) ? q : (z == 1) ? k : v;
    ushort* out = (z == 0) ? xq : (z == 1) ? xk : xv;
    int i = (blockIdx.x & 2047) * 256 + threadIdx.x;
    const float4* p = (const float4*)in + (size_t)i * 2;
    float4 a = p[0], b = p[1];
    uint tmp[4] = { pkbf(a.x, a.y), pkbf(a.z, a.w), pkbf(b.x, b.y), pkbf(b.z, b.w) };
    *(uint4*)(out + (size_t)i * 8) = *(uint4*)tmp;
  } else {
    int idx = blockIdx.x - 6144;
    int z = idx >> 10;
    int rr = idx & 1023;
    const float* W = (z == 0) ? W0 : (z == 1) ? W1 : (z == 2) ? W2 : W3;
    ushort* T = (z == 0) ? T0 : (z == 1) ? T1 : (z == 2) ? T2 : T3;
    int tx = threadIdx.x & 31, ty = threadIdx.x >> 5;   // 32 x 8
    int n0 = (rr & 31) * 32, k0 = (rr >> 5) * 32;
#pragma unroll
    for (int i = 0; i < 4; i++)
      tile[ty + i * 8][tx] = W[(size_t)(k0 + ty + i * 8) * DDIM + n0 + tx];
    __syncthreads();
#pragma unroll
    for (int i = 0; i < 4; i++)
      T[(size_t)(n0 + ty + i * 8) * DDIM + k0 + tx] = f2bf(tile[tx][ty + i * 8]);
  }
}

// ---------------- fused Q/K/V projection GEMM (m97 structure, XCD-local groups) --
// flat grid 768: xcd = id&7 owns groups g = xcd*12 + slot (slot = (id>>3)>>3),
// group = (m-panel y, tensor z), all 8 n-blocks x = (id>>3)&7 co-resident on xcd.
// out z=0: Qh[bh][2048][64], z=1: Kh[bh][2048][64], z=2: Vt[bh][64][2048]
__global__ __launch_bounds__(256) void qkv_gemm_kernel(
    const ushort* __restrict__ Xq, const ushort* __restrict__ Xk, const ushort* __restrict__ Xv,
    const ushort* __restrict__ Wqt, const ushort* __restrict__ Wkt, const ushort* __restrict__ Wvt,
    const float* __restrict__ bqp, const float* __restrict__ bkp, const float* __restrict__ bvp,
    ushort* __restrict__ Qh, ushort* __restrict__ Kh, ushort* __restrict__ Vtg) {
  const int id = blockIdx.x;
  const int xcd = id & 7;
  const int rest = id >> 3;          // 0..95
  const int xblk = rest & 7;         // n-block 0..7
  const int slot = rest >> 3;        // 0..11
  const int g = xcd * 12 + slot;     // 0..95
  const int yblk = g & 31;           // m-panel 0..31
  const int z = g >> 5;              // tensor 0..2

  const ushort* A  = (z == 0) ? Xq  : (z == 1) ? Xk  : Xv;
  const ushort* Bt = (z == 0) ? Wqt : (z == 1) ? Wkt : Wvt;
  const float* bias = (z == 0) ? bqp : (z == 1) ? bkp : bvp;
  const int K = DDIM;

  __shared__ __align__(16) ushort As[128 * 32];
  __shared__ __align__(16) ushort Bs[128 * 32];
  const int tid = threadIdx.x;
  const int w = tid >> 6, lane = tid & 63;
  const int m0 = yblk * 128, n0 = xblk * 128;
  const int wr = (w >> 1) * 64, wc = (w & 1) * 64;
  const int l4 = lane >> 4, l15 = lane & 15;
  const int srow = lane >> 2;
  const int scol = (lane & 3) * 8;

  f32x4 zero = {0.f, 0.f, 0.f, 0.f};
  f32x4 acc[4][4];
#pragma unroll
  for (int i = 0; i < 4; i++)
#pragma unroll
    for (int j = 0; j < 4; j++) acc[i][j] = zero;

  for (int k0 = 0; k0 < K; k0 += 32) {
#pragma unroll
    for (int it = 0; it < 2; ++it) {
      int r = it * 64 + w * 16;
      gload_lds16(A + (size_t)(m0 + r + srow) * K + k0 + scol, &As[r * 32]);
      gload_lds16(Bt + (size_t)(n0 + r + srow) * K + k0 + scol, &Bs[r * 32]);
    }
    __syncthreads();
    bf16x8 af[4], bfr[4];
#pragma unroll
    for (int m = 0; m < 4; m++)
      af[m] = *(const bf16x8*)&As[(wr + m * 16 + l15) * 32 + l4 * 8];
#pragma unroll
    for (int n = 0; n < 4; n++)
      bfr[n] = *(const bf16x8*)&Bs[(wc + n * 16 + l15) * 32 + l4 * 8];
#pragma unroll
    for (int m = 0; m < 4; m++)
#pragma unroll
      for (int n = 0; n < 4; n++)
        acc[m][n] = __builtin_amdgcn_mfma_f32_16x16x32_bf16(af[m], bfr[n], acc[m][n], 0, 0, 0);
    __syncthreads();
  }

  if (z != 2) {
    ushort* outp = (z == 0) ? Qh : Kh;
#pragma unroll
    for (int m = 0; m < 4; m++) {
#pragma unroll
      for (int n = 0; n < 4; n++) {
        int col = n0 + wc + n * 16 + l15;
        float bv = bias[col];
        int hh = col >> 6, dd = col & 63;
#pragma unroll
        for (int r = 0; r < 4; r++) {
          int row = m0 + wr + m * 16 + l4 * 4 + r;
          int bb = row >> 11, s = row & (SS - 1);
          outp[((size_t)(bb * HH + hh) * SS + s) * DEPTH + dd] = f2bf(acc[m][n][r] + bv);
        }
      }
    }
  } else {
    // V^T epilogue: per-wave LDS-bounce transpose -> coalesced 16B stores
    ushort* wtile = (w < 2) ? &As[w * 2048] : &Bs[(w - 2) * 2048];  // 32 d x 64 s
    const int gcol0 = n0 + wc;
    const int hh = gcol0 >> 6;
    const int bb = m0 >> 11;
    const int s0g = (m0 + wr) & (SS - 1);
#pragma unroll
    for (int p = 0; p < 2; ++p) {
#pragma unroll
      for (int nn = 0; nn < 2; ++nn) {
        int n = p * 2 + nn;
        int dloc = nn * 16 + l15;
        float bv = bias[gcol0 + p * 32 + dloc];
#pragma unroll
        for (int m = 0; m < 4; m++) {
#pragma unroll
          for (int rr = 0; rr < 4; rr += 2) {
            int sloc = m * 16 + l4 * 4 + rr;
            int gg = (sloc >> 3) ^ (dloc & 7);
            uint pk = pkbf(acc[m][n][rr] + bv, acc[m][n][rr + 1] + bv);
            *(uint*)&wtile[dloc * 64 + gg * 8 + (sloc & 7)] = pk;
          }
        }
      }
      __syncthreads();
#pragma unroll
      for (int i = 0; i < 4; ++i) {
        int dloc = (lane >> 3) + i * 8;
        int gg = (lane & 7) ^ (dloc & 7);
        bf16x8 val = *(const bf16x8*)&wtile[dloc * 64 + gg * 8];
        int dglob = p * 32 + dloc;
        size_t addr = ((size_t)(bb * HH + hh) * DEPTH + dglob) * SS + s0g + (lane & 7) * 8;
        *(bf16x8*)&Vtg[addr] = val;
      }
      __syncthreads();
    }
  }
}

// ---------------- output GEMM: 128x64 tile, XCD-local m-panels -------------------
// flat grid 512: xcd = id&7 owns m-panels y = xcd*4 + slot; x = (id>>3)&15.
__global__ __launch_bounds__(256, 2) void out_gemm_kernel(
    const ushort* __restrict__ A, const ushort* __restrict__ Bt,
    const float* __restrict__ bias, float* __restrict__ out,
    int M, int N, int K) {
  __shared__ __align__(16) ushort As[128 * 32];
  __shared__ __align__(16) ushort Bs[64 * 32];
  const int id = blockIdx.x;
  const int xcd = id & 7;
  const int rest = id >> 3;          // 0..63
  const int xblk = rest & 15;        // n-block 0..15
  const int slot = rest >> 4;        // 0..3
  const int yblk = xcd * 4 + slot;   // m-panel 0..31

  const int tid = threadIdx.x;
  const int w = tid >> 6, lane = tid & 63;
  const int m0 = yblk * 128, n0 = xblk * 64;
  const int wr = (w >> 1) * 64, wc = (w & 1) * 32;
  const int l4 = lane >> 4, l15 = lane & 15;
  const int srow = lane >> 2;
  const int scol = (lane & 3) * 8;

  f32x4 zero = {0.f, 0.f, 0.f, 0.f};
  f32x4 acc[4][2];
#pragma unroll
  for (int i = 0; i < 4; i++)
#pragma unroll
    for (int j = 0; j < 2; j++) acc[i][j] = zero;

  for (int k0 = 0; k0 < K; k0 += 32) {
#pragma unroll
    for (int it = 0; it < 2; ++it) {
      int r = it * 64 + w * 16;
      gload_lds16(A + (size_t)(m0 + r + srow) * K + k0 + scol, &As[r * 32]);
    }
    gload_lds16(Bt + (size_t)(n0 + w * 16 + srow) * K + k0 + scol, &Bs[(w * 16) * 32]);
    __syncthreads();
    bf16x8 af[4], bfr[2];
#pragma unroll
    for (int m = 0; m < 4; m++)
      af[m] = *(const bf16x8*)&As[(wr + m * 16 + l15) * 32 + l4 * 8];
#pragma unroll
    for (int n = 0; n < 2; n++)
      bfr[n] = *(const bf16x8*)&Bs[(wc + n * 16 + l15) * 32 + l4 * 8];
#pragma unroll
    for (int m = 0; m < 4; m++)
#pragma unroll
      for (int n = 0; n < 2; n++)
        acc[m][n] = __builtin_amdgcn_mfma_f32_16x16x32_bf16(af[m], bfr[n], acc[m][n], 0, 0, 0);
    __syncthreads();
  }

#pragma unroll
  for (int m = 0; m < 4; m++) {
#pragma unroll
    for (int n = 0; n < 2; n++) {
      int col = n0 + wc + n * 16 + l15;
      float bv = bias[col];
#pragma unroll
      for (int r = 0; r < 4; r++) {
        int row = m0 + wr + m * 16 + l4 * 4 + r;
        out[(size_t)row * N + col] = acc[m][n][r] + bv;
      }
    }
  }
}

// ---------------- causal flash attention: 1024 LPT-ordered blocks, 4/CU ---------
// Qh,Kh: [bh][2048][64] bf16 ; Vt: [bh][64][2048] bf16 ; ctx: [4096][1024] bf16
__global__ __launch_bounds__(256, 4) void attn_kernel(
    const ushort* __restrict__ Qh, const ushort* __restrict__ Kh,
    const ushort* __restrict__ Vt, ushort* __restrict__ ctx) {
  __shared__ __align__(16) ushort Ks[2][64 * 64];   // [kv][d], XOR-swizzled
  __shared__ __align__(16) ushort Vs[2][64 * 64];   // [d][kv], XOR-swizzled
  __shared__ __align__(16) ushort Ps[4][16 * 64];   // per-wave P, XOR-swizzled
  const int tid = threadIdx.x;
  const int w = tid >> 6, lane = tid & 63;
  const int l4 = lane >> 4, l15 = lane & 15;
  const float CE = 0.18033688f;                     // 0.125 * log2(e)

  const int xcd = blockIdx.x & 7;
  const int local = blockIdx.x >> 3;                // 0..127
  const int bh = xcd * 4 + (local & 3);
  const int chunk = 31 - (local >> 2);
  const int b = bh >> 4, h = bh & 15;
  const size_t qkbase = (size_t)bh * SS * DEPTH;
  const size_t vbase  = (size_t)bh * DEPTH * SS;

  const int srow_w = w * 8 + (lane >> 3);
  const int colb_lin = (lane & 7) * 16;
  const int swz_rd = (l15 & 7) << 3;

  const int q0 = chunk * 64 + w * 16;
  const int nt = chunk + 1;

  bf16x8 aq[2];
#pragma unroll
  for (int cc = 0; cc < 2; cc++)
    aq[cc] = *(const bf16x8*)&Qh[qkbase + (size_t)(q0 + l15) * DEPTH + cc * 32 + l4 * 8];

  f32x4 zero = {0.f, 0.f, 0.f, 0.f};
  f32x4 o[4];
  float m_run = -__builtin_inff(), l_run = 0.f;
#pragma unroll
  for (int d = 0; d < 4; d++) o[d] = zero;

  int buf = 0;
#pragma unroll
  for (int it = 0; it < 2; ++it) {
    int row = it * 32 + srow_w;
    int col_e = (colb_lin ^ ((row & 7) << 4)) >> 1;
    int ldsoff = it * 2048 + w * 512;
    gload_lds16(Kh + qkbase + (size_t)row * DEPTH + col_e, &Ks[0][ldsoff]);
    gload_lds16(Vt + vbase + (size_t)row * SS + col_e, &Vs[0][ldsoff]);
  }
  __syncthreads();

  for (int t = 0; t < nt; ++t) {
    if (t + 1 < nt) {
      const int kv1 = (t + 1) * 64;
#pragma unroll
      for (int it = 0; it < 2; ++it) {
        int row = it * 32 + srow_w;
        int col_e = (colb_lin ^ ((row & 7) << 4)) >> 1;
        int ldsoff = it * 2048 + w * 512;
        gload_lds16(Kh + qkbase + (size_t)(kv1 + row) * DEPTH + col_e, &Ks[buf ^ 1][ldsoff]);
        gload_lds16(Vt + vbase + (size_t)row * SS + kv1 + col_e, &Vs[buf ^ 1][ldsoff]);
      }
    }

    const int kv0 = t * 64;
    f32x4 s[4];
    __builtin_amdgcn_s_setprio(1);
#pragma unroll
    for (int n = 0; n < 4; n++) {
      f32x4 zacc = zero;
      int kr = n * 16 + l15;
#pragma unroll
      for (int cc = 0; cc < 2; cc++) {
        bf16x8 bk = *(const bf16x8*)&Ks[buf][kr * 64 + ((cc * 32 + l4 * 8) ^ swz_rd)];
        zacc = __builtin_amdgcn_mfma_f32_16x16x32_bf16(bk, aq[cc], zacc, 0, 0, 0);
      }
      s[n] = zacc;
    }
    __builtin_amdgcn_s_setprio(0);

    const int qg = q0 + l15;
    if (t == nt - 1) {
#pragma unroll
      for (int n = 0; n < 4; n++) {
        int kb = kv0 + n * 16 + l4 * 4;
#pragma unroll
        for (int r = 0; r < 4; r++)
          if (kb + r > qg) s[n][r] = -1e9f;
      }
    }

    float mx = -__builtin_inff();
#pragma unroll
    for (int n = 0; n < 4; n++)
      mx = fmaxf(mx, fmaxf(fmaxf(s[n][0], s[n][1]), fmaxf(s[n][2], s[n][3])));
    mx = fmaxf(mx, __shfl_xor(mx, 16));
    mx = fmaxf(mx, __shfl_xor(mx, 32));
    if (!__all(mx - m_run <= 44.36f)) {      // defer-max: P bounded by 2^8
      float mnew = fmaxf(m_run, mx);
      float alpha = exp2f((m_run - mnew) * CE);
      m_run = mnew;
      l_run *= alpha;
#pragma unroll
      for (int d = 0; d < 4; d++) o[d] *= alpha;
    }
    float mc = m_run * CE;
    float rs = 0.f;
#pragma unroll
    for (int n = 0; n < 4; n++)
#pragma unroll
      for (int r = 0; r < 4; r++) {
        float p = exp2f(s[n][r] * CE - mc);
        s[n][r] = p;
        rs += p;
      }
    l_run += rs;

    ushort* Pw = &Ps[w][0];
#pragma unroll
    for (int n = 0; n < 4; n++) {
      int col = (n * 16 + l4 * 4) ^ swz_rd;
      *(uint*)&Pw[l15 * 64 + col]     = pkbf(s[n][0], s[n][1]);
      *(uint*)&Pw[l15 * 64 + col + 2] = pkbf(s[n][2], s[n][3]);
    }

    bf16x8 pa[2];
#pragma unroll
    for (int cc = 0; cc < 2; cc++)
      pa[cc] = *(const bf16x8*)&Pw[l15 * 64 + ((cc * 32 + l4 * 8) ^ swz_rd)];

    __builtin_amdgcn_s_setprio(1);
#pragma unroll
    for (int d = 0; d < 4; d++) {
      int dr = d * 16 + l15;
#pragma unroll
      for (int cc = 0; cc < 2; cc++) {
        bf16x8 av = *(const bf16x8*)&Vs[buf][dr * 64 + ((cc * 32 + l4 * 8) ^ swz_rd)];
        o[d] = __builtin_amdgcn_mfma_f32_16x16x32_bf16(av, pa[cc], o[d], 0, 0, 0);
      }
    }
    __builtin_amdgcn_s_setprio(0);

    __syncthreads();
    buf ^= 1;
  }

  float lv = l_run;
  lv += __shfl_xor(lv, 16);
  lv += __shfl_xor(lv, 32);
  float inv = 1.f / lv;
  size_t rowbase = ((size_t)(b * SS + q0 + l15)) * DDIM + h * DEPTH;
#pragma unroll
  for (int d = 0; d < 4; d++) {
    *(uint*)&ctx[rowbase + d * 16 + l4 * 4]     = pkbf(o[d][0] * inv, o[d][1] * inv);
    *(uint*)&ctx[rowbase + d * 16 + l4 * 4 + 2] = pkbf(o[d][2] * inv, o[d][3] * inv);
  }
}

extern "C" void kernel_launch(void* const* d_in, const int* in_sizes, int n_in,
                              void* d_out, int out_size, void* d_ws, size_t ws_size,
                              hipStream_t stream) {
  const float* query = (const float*)d_in[0];
  const float* key_  = (const float*)d_in[1];
  const float* value = (const float*)d_in[2];
  const float* Wq = (const float*)d_in[4];
  const float* Wk = (const float*)d_in[5];
  const float* Wv = (const float*)d_in[6];
  const float* Wo = (const float*)d_in[7];
  const float* bq = (const float*)d_in[8];
  const float* bk = (const float*)d_in[9];
  const float* bv = (const float*)d_in[10];
  const float* bo = (const float*)d_in[11];

  char* ws = (char*)d_ws;
  const size_t MB = 1u << 20;
  ushort* Xq  = (ushort*)(ws + 0 * MB);
  ushort* Xk  = (ushort*)(ws + 8 * MB);
  ushort* Xv  = (ushort*)(ws + 16 * MB);
  ushort* Wqt = (ushort*)(ws + 24 * MB);
  ushort* Wkt = (ushort*)(ws + 26 * MB);
  ushort* Wvt = (ushort*)(ws + 28 * MB);
  ushort* Wot = (ushort*)(ws + 30 * MB);
  ushort* Qh  = (ushort*)(ws + 32 * MB);   // [bh][2048][64]
  ushort* Kh  = (ushort*)(ws + 40 * MB);   // [bh][2048][64]
  ushort* Vtg = (ushort*)(ws + 48 * MB);   // [bh][64][2048]
  ushort* Cb  = (ushort*)(ws + 56 * MB);   // [4096][1024]

  prep_kernel<<<6144 + 4096, 256, 0, stream>>>(query, key_, value, Xq, Xk, Xv,
                                               Wq, Wk, Wv, Wo, Wqt, Wkt, Wvt, Wot);

  qkv_gemm_kernel<<<768, 256, 0, stream>>>(
      Xq, Xk, Xv, Wqt, Wkt, Wvt, bq, bk, bv, Qh, Kh, Vtg);

  attn_kernel<<<1024, 256, 0, stream>>>(Qh, Kh, Vtg, Cb);

  out_gemm_kernel<<<512, 256, 0, stream>>>(
      Cb, Wot, bo, (float*)d_out, MROWS, DDIM, DDIM);
}

// Round 7
// 118.152 us; speedup vs baseline: 1.3104x; 1.0845x over previous
//
#include <hip/hip_runtime.h>
#include <hip/hip_bf16.h>
#include <stdint.h>

#define BB 2
#define SS 2048
#define DDIM 1024
#define HH 16
#define DEPTH 64
#define MROWS (BB*SS)   // 4096

typedef short bf16x8 __attribute__((ext_vector_type(8)));
typedef float f32x4 __attribute__((ext_vector_type(4)));

__device__ inline ushort f2bf(float f) {
  union { float f; unsigned u; } v; v.f = f;
  unsigned r = v.u + 0x7fffu + ((v.u >> 16) & 1u);
  return (ushort)(r >> 16);
}

// HW packed f32x2 -> bf16x2 (RTNE), low = a, high = b  [m214 T12]
__device__ inline uint pkbf(float a, float b) {
  uint r;
  asm("v_cvt_pk_bf16_f32 %0, %1, %2" : "=v"(r) : "v"(a), "v"(b));
  return r;
}

__device__ inline void gload_lds16(const void* g, void* l) {
  __builtin_amdgcn_global_load_lds(
      (const __attribute__((address_space(1))) unsigned*)g,
      (__attribute__((address_space(3))) unsigned*)l,
      16, 0, 0);
}

// ---------------- weight transpose + convert: T[n][k] = W[k][n] ----------------
__global__ void wprep_kernel(const float* __restrict__ W0, const float* __restrict__ W1,
                             const float* __restrict__ W2, const float* __restrict__ W3,
                             ushort* __restrict__ T0, ushort* __restrict__ T1,
                             ushort* __restrict__ T2, ushort* __restrict__ T3) {
  __shared__ float tile[32][33];
  int z = blockIdx.x >> 10;
  int rr = blockIdx.x & 1023;
  const float* W = (z == 0) ? W0 : (z == 1) ? W1 : (z == 2) ? W2 : W3;
  ushort* T = (z == 0) ? T0 : (z == 1) ? T1 : (z == 2) ? T2 : T3;
  int tx = threadIdx.x & 31, ty = threadIdx.x >> 5;   // 32 x 8
  int n0 = (rr & 31) * 32, k0 = (rr >> 5) * 32;
#pragma unroll
  for (int i = 0; i < 4; i++)
    tile[ty + i * 8][tx] = W[(size_t)(k0 + ty + i * 8) * DDIM + n0 + tx];
  __syncthreads();
#pragma unroll
  for (int i = 0; i < 4; i++)
    T[(size_t)(n0 + ty + i * 8) * DDIM + k0 + tx] = f2bf(tile[tx][ty + i * 8]);
}

// ---------------- fused Q/K/V projection GEMM, BK=64, fp32-A reg-staged ----------
// A read directly from fp32 inputs (cvt fused); B (bf16 W^T) via global_load_lds.
// flat grid 768, XCD-local groups. out z=0: Qh[bh][s][64], z=1: Kh, z=2: Vt[bh][64][s]
__global__ __launch_bounds__(256, 3) void qkv_gemm_kernel(
    const float* __restrict__ Aq, const float* __restrict__ Ak, const float* __restrict__ Av,
    const ushort* __restrict__ Wqt, const ushort* __restrict__ Wkt, const ushort* __restrict__ Wvt,
    const float* __restrict__ bqp, const float* __restrict__ bkp, const float* __restrict__ bvp,
    ushort* __restrict__ Qh, ushort* __restrict__ Kh, ushort* __restrict__ Vtg) {
  const int id = blockIdx.x;
  const int xcd = id & 7;
  const int rest = id >> 3;          // 0..95
  const int xblk = rest & 7;         // n-block 0..7
  const int slot = rest >> 3;        // 0..11
  const int g = xcd * 12 + slot;     // 0..95
  const int yblk = g & 31;           // m-panel 0..31
  const int z = g >> 5;              // tensor 0..2

  const float*  Ap = (z == 0) ? Aq  : (z == 1) ? Ak  : Av;
  const ushort* Bt = (z == 0) ? Wqt : (z == 1) ? Wkt : Wvt;
  const float* bias = (z == 0) ? bqp : (z == 1) ? bkp : bvp;

  __shared__ __align__(16) ushort As[128 * 64];   // 16 KB
  __shared__ __align__(16) ushort Bs[128 * 64];   // 16 KB
  const int tid = threadIdx.x;
  const int w = tid >> 6, lane = tid & 63;
  const int m0 = yblk * 128, n0 = xblk * 128;
  const int wr = (w >> 1) * 64, wc = (w & 1) * 64;
  const int l4 = lane >> 4, l15 = lane & 15;
  const int row16 = tid >> 4;          // 0..15
  const int col4 = (tid & 15) * 4;     // fp32/bf16 col, 16B fp32 chunk
  const int srow8 = w * 8 + (lane >> 3);
  const int scol8 = (lane & 7) * 8;

  f32x4 zero = {0.f, 0.f, 0.f, 0.f};
  f32x4 acc[4][4];
#pragma unroll
  for (int i = 0; i < 4; i++)
#pragma unroll
    for (int j = 0; j < 4; j++) acc[i][j] = zero;

  float4 areg[8];
#pragma unroll
  for (int j = 0; j < 8; ++j)
    areg[j] = *(const float4*)&Ap[(size_t)(m0 + j * 16 + row16) * DDIM + col4];

  for (int t = 0; t < 16; ++t) {
    // stage B tile (bf16, linear LDS)
#pragma unroll
    for (int it = 0; it < 4; ++it)
      gload_lds16(Bt + (size_t)(n0 + it * 32 + srow8) * DDIM + t * 64 + scol8,
                  &Bs[(it * 32 + w * 8) * 64]);
    // write A tile from regs (cvt fp32->bf16)
#pragma unroll
    for (int j = 0; j < 8; ++j) {
      uint2 pk;
      pk.x = pkbf(areg[j].x, areg[j].y);
      pk.y = pkbf(areg[j].z, areg[j].w);
      *(uint2*)&As[(j * 16 + row16) * 64 + col4] = pk;
    }
    __syncthreads();
    // issue A loads for t+1 (in flight across the MFMA block)
    if (t + 1 < 16) {
#pragma unroll
      for (int j = 0; j < 8; ++j)
        areg[j] = *(const float4*)&Ap[(size_t)(m0 + j * 16 + row16) * DDIM + (t + 1) * 64 + col4];
    }
#pragma unroll
    for (int kk = 0; kk < 2; ++kk) {
      bf16x8 af[4], bfr[4];
#pragma unroll
      for (int m = 0; m < 4; m++)
        af[m] = *(const bf16x8*)&As[(wr + m * 16 + l15) * 64 + kk * 32 + l4 * 8];
#pragma unroll
      for (int n = 0; n < 4; n++)
        bfr[n] = *(const bf16x8*)&Bs[(wc + n * 16 + l15) * 64 + kk * 32 + l4 * 8];
#pragma unroll
      for (int m = 0; m < 4; m++)
#pragma unroll
        for (int n = 0; n < 4; n++)
          acc[m][n] = __builtin_amdgcn_mfma_f32_16x16x32_bf16(af[m], bfr[n], acc[m][n], 0, 0, 0);
    }
    __syncthreads();
  }

  if (z != 2) {
    // Q/K epilogue: wave-private 64x64 LDS bounce (XOR-swizzled) -> coalesced 16B stores
    ushort* outp = (z == 0) ? Qh : Kh;
    ushort* wtile = (w < 2) ? &As[w * 4096] : &Bs[(w - 2) * 4096];
    const int gcol0 = n0 + wc;          // 64-aligned -> one head per wave
    const int hh = gcol0 >> 6;
    const int bb = m0 >> 11;
    const int s0g = (m0 + wr) & (SS - 1);
#pragma unroll
    for (int m = 0; m < 4; m++) {
#pragma unroll
      for (int n = 0; n < 4; n++) {
        int dloc = n * 16 + l15;
        float bv = bias[gcol0 + dloc];
#pragma unroll
        for (int r = 0; r < 4; r++) {
          int sloc = m * 16 + l4 * 4 + r;
          wtile[sloc * 64 + (dloc ^ ((sloc & 7) << 3))] = f2bf(acc[m][n][r] + bv);
        }
      }
    }
    // wave-private, DS in-order: no barrier needed
#pragma unroll
    for (int i = 0; i < 8; ++i) {
      int srow = i * 8 + (lane >> 3);
      int dch = (lane & 7) * 8;
      bf16x8 val = *(const bf16x8*)&wtile[srow * 64 + (dch ^ ((srow & 7) << 3))];
      *(bf16x8*)&outp[((size_t)(bb * HH + hh) * SS + s0g + srow) * DEPTH + dch] = val;
    }
  } else {
    // V^T epilogue: per-wave LDS-bounce transpose -> coalesced 16B stores
    ushort* wtile = (w < 2) ? &As[w * 2048] : &Bs[(w - 2) * 2048];  // 32 d x 64 s
    const int gcol0 = n0 + wc;
    const int hh = gcol0 >> 6;
    const int bb = m0 >> 11;
    const int s0g = (m0 + wr) & (SS - 1);
#pragma unroll
    for (int p = 0; p < 2; ++p) {
#pragma unroll
      for (int nn = 0; nn < 2; ++nn) {
        int n = p * 2 + nn;
        int dloc = nn * 16 + l15;
        float bv = bias[gcol0 + p * 32 + dloc];
#pragma unroll
        for (int m = 0; m < 4; m++) {
#pragma unroll
          for (int rr = 0; rr < 4; rr += 2) {
            int sloc = m * 16 + l4 * 4 + rr;
            int gg = (sloc >> 3) ^ (dloc & 7);
            uint pk = pkbf(acc[m][n][rr] + bv, acc[m][n][rr + 1] + bv);
            *(uint*)&wtile[dloc * 64 + gg * 8 + (sloc & 7)] = pk;
          }
        }
      }
      __syncthreads();
#pragma unroll
      for (int i = 0; i < 4; ++i) {
        int dloc = (lane >> 3) + i * 8;
        int gg = (lane & 7) ^ (dloc & 7);
        bf16x8 val = *(const bf16x8*)&wtile[dloc * 64 + gg * 8];
        int dglob = p * 32 + dloc;
        size_t addr = ((size_t)(bb * HH + hh) * DEPTH + dglob) * SS + s0g + (lane & 7) * 8;
        *(bf16x8*)&Vtg[addr] = val;
      }
      __syncthreads();
    }
  }
}

// ---------------- output GEMM: 128x64 tile, BK=64, XCD-local m-panels ------------
__global__ __launch_bounds__(256, 2) void out_gemm_kernel(
    const ushort* __restrict__ A, const ushort* __restrict__ Bt,
    const float* __restrict__ bias, float* __restrict__ out,
    int M, int N, int K) {
  __shared__ __align__(16) ushort As[128 * 64];   // 16 KB
  __shared__ __align__(16) ushort Bs[64 * 64];    // 8 KB
  const int id = blockIdx.x;
  const int xcd = id & 7;
  const int rest = id >> 3;          // 0..63
  const int xblk = rest & 15;        // n-block 0..15
  const int slot = rest >> 4;        // 0..3
  const int yblk = xcd * 4 + slot;   // m-panel 0..31

  const int tid = threadIdx.x;
  const int w = tid >> 6, lane = tid & 63;
  const int m0 = yblk * 128, n0 = xblk * 64;
  const int wr = (w >> 1) * 64, wc = (w & 1) * 32;
  const int l4 = lane >> 4, l15 = lane & 15;
  const int srow8 = w * 8 + (lane >> 3);
  const int scol8 = (lane & 7) * 8;

  f32x4 zero = {0.f, 0.f, 0.f, 0.f};
  f32x4 acc[4][2];
#pragma unroll
  for (int i = 0; i < 4; i++)
#pragma unroll
    for (int j = 0; j < 2; j++) acc[i][j] = zero;

  for (int t = 0; t < 16; ++t) {
#pragma unroll
    for (int it = 0; it < 4; ++it)
      gload_lds16(A + (size_t)(m0 + it * 32 + srow8) * K + t * 64 + scol8,
                  &As[(it * 32 + w * 8) * 64]);
#pragma unroll
    for (int it = 0; it < 2; ++it)
      gload_lds16(Bt + (size_t)(n0 + it * 32 + srow8) * K + t * 64 + scol8,
                  &Bs[(it * 32 + w * 8) * 64]);
    __syncthreads();
#pragma unroll
    for (int kk = 0; kk < 2; ++kk) {
      bf16x8 af[4], bfr[2];
#pragma unroll
      for (int m = 0; m < 4; m++)
        af[m] = *(const bf16x8*)&As[(wr + m * 16 + l15) * 64 + kk * 32 + l4 * 8];
#pragma unroll
      for (int n = 0; n < 2; n++)
        bfr[n] = *(const bf16x8*)&Bs[(wc + n * 16 + l15) * 64 + kk * 32 + l4 * 8];
#pragma unroll
      for (int m = 0; m < 4; m++)
#pragma unroll
        for (int n = 0; n < 2; n++)
          acc[m][n] = __builtin_amdgcn_mfma_f32_16x16x32_bf16(af[m], bfr[n], acc[m][n], 0, 0, 0);
    }
    __syncthreads();
  }

#pragma unroll
  for (int m = 0; m < 4; m++) {
#pragma unroll
    for (int n = 0; n < 2; n++) {
      int col = n0 + wc + n * 16 + l15;
      float bv = bias[col];
#pragma unroll
      for (int r = 0; r < 4; r++) {
        int row = m0 + wr + m * 16 + l4 * 4 + r;
        out[(size_t)row * N + col] = acc[m][n][r] + bv;
      }
    }
  }
}

// ---------------- causal flash attention: 1024 LPT-ordered blocks, 4/CU ---------
__global__ __launch_bounds__(256, 4) void attn_kernel(
    const ushort* __restrict__ Qh, const ushort* __restrict__ Kh,
    const ushort* __restrict__ Vt, ushort* __restrict__ ctx) {
  __shared__ __align__(16) ushort Ks[2][64 * 64];   // [kv][d], XOR-swizzled
  __shared__ __align__(16) ushort Vs[2][64 * 64];   // [d][kv], XOR-swizzled
  __shared__ __align__(16) ushort Ps[4][16 * 64];   // per-wave P, XOR-swizzled
  const int tid = threadIdx.x;
  const int w = tid >> 6, lane = tid & 63;
  const int l4 = lane >> 4, l15 = lane & 15;
  const float CE = 0.18033688f;                     // 0.125 * log2(e)

  const int xcd = blockIdx.x & 7;
  const int local = blockIdx.x >> 3;                // 0..127
  const int bh = xcd * 4 + (local & 3);
  const int chunk = 31 - (local >> 2);
  const int b = bh >> 4, h = bh & 15;
  const size_t qkbase = (size_t)bh * SS * DEPTH;
  const size_t vbase  = (size_t)bh * DEPTH * SS;

  const int srow_w = w * 8 + (lane >> 3);
  const int colb_lin = (lane & 7) * 16;
  const int swz_rd = (l15 & 7) << 3;

  const int q0 = chunk * 64 + w * 16;
  const int nt = chunk + 1;

  bf16x8 aq[2];
#pragma unroll
  for (int cc = 0; cc < 2; cc++)
    aq[cc] = *(const bf16x8*)&Qh[qkbase + (size_t)(q0 + l15) * DEPTH + cc * 32 + l4 * 8];

  f32x4 zero = {0.f, 0.f, 0.f, 0.f};
  f32x4 o[4];
  float m_run = -__builtin_inff(), l_run = 0.f;
#pragma unroll
  for (int d = 0; d < 4; d++) o[d] = zero;

  int buf = 0;
#pragma unroll
  for (int it = 0; it < 2; ++it) {
    int row = it * 32 + srow_w;
    int col_e = (colb_lin ^ ((row & 7) << 4)) >> 1;
    int ldsoff = it * 2048 + w * 512;
    gload_lds16(Kh + qkbase + (size_t)row * DEPTH + col_e, &Ks[0][ldsoff]);
    gload_lds16(Vt + vbase + (size_t)row * SS + col_e, &Vs[0][ldsoff]);
  }
  __syncthreads();

  for (int t = 0; t < nt; ++t) {
    if (t + 1 < nt) {
      const int kv1 = (t + 1) * 64;
#pragma unroll
      for (int it = 0; it < 2; ++it) {
        int row = it * 32 + srow_w;
        int col_e = (colb_lin ^ ((row & 7) << 4)) >> 1;
        int ldsoff = it * 2048 + w * 512;
        gload_lds16(Kh + qkbase + (size_t)(kv1 + row) * DEPTH + col_e, &Ks[buf ^ 1][ldsoff]);
        gload_lds16(Vt + vbase + (size_t)row * SS + kv1 + col_e, &Vs[buf ^ 1][ldsoff]);
      }
    }

    const int kv0 = t * 64;
    f32x4 s[4];
    __builtin_amdgcn_s_setprio(1);
#pragma unroll
    for (int n = 0; n < 4; n++) {
      f32x4 zacc = zero;
      int kr = n * 16 + l15;
#pragma unroll
      for (int cc = 0; cc < 2; cc++) {
        bf16x8 bk = *(const bf16x8*)&Ks[buf][kr * 64 + ((cc * 32 + l4 * 8) ^ swz_rd)];
        zacc = __builtin_amdgcn_mfma_f32_16x16x32_bf16(bk, aq[cc], zacc, 0, 0, 0);
      }
      s[n] = zacc;
    }
    __builtin_amdgcn_s_setprio(0);

    const int qg = q0 + l15;
    if (t == nt - 1) {
#pragma unroll
      for (int n = 0; n < 4; n++) {
        int kb = kv0 + n * 16 + l4 * 4;
#pragma unroll
        for (int r = 0; r < 4; r++)
          if (kb + r > qg) s[n][r] = -1e9f;
      }
    }

    float mx = -__builtin_inff();
#pragma unroll
    for (int n = 0; n < 4; n++)
      mx = fmaxf(mx, fmaxf(fmaxf(s[n][0], s[n][1]), fmaxf(s[n][2], s[n][3])));
    mx = fmaxf(mx, __shfl_xor(mx, 16));
    mx = fmaxf(mx, __shfl_xor(mx, 32));
    if (!__all(mx - m_run <= 44.36f)) {      // defer-max: P bounded by 2^8
      float mnew = fmaxf(m_run, mx);
      float alpha = exp2f((m_run - mnew) * CE);
      m_run = mnew;
      l_run *= alpha;
#pragma unroll
      for (int d = 0; d < 4; d++) o[d] *= alpha;
    }
    float mc = m_run * CE;
    float rs = 0.f;
#pragma unroll
    for (int n = 0; n < 4; n++)
#pragma unroll
      for (int r = 0; r < 4; r++) {
        float p = exp2f(s[n][r] * CE - mc);
        s[n][r] = p;
        rs += p;
      }
    l_run += rs;

    ushort* Pw = &Ps[w][0];
#pragma unroll
    for (int n = 0; n < 4; n++) {
      int col = (n * 16 + l4 * 4) ^ swz_rd;
      *(uint*)&Pw[l15 * 64 + col]     = pkbf(s[n][0], s[n][1]);
      *(uint*)&Pw[l15 * 64 + col + 2] = pkbf(s[n][2], s[n][3]);
    }

    bf16x8 pa[2];
#pragma unroll
    for (int cc = 0; cc < 2; cc++)
      pa[cc] = *(const bf16x8*)&Pw[l15 * 64 + ((cc * 32 + l4 * 8) ^ swz_rd)];

    __builtin_amdgcn_s_setprio(1);
#pragma unroll
    for (int d = 0; d < 4; d++) {
      int dr = d * 16 + l15;
#pragma unroll
      for (int cc = 0; cc < 2; cc++) {
        bf16x8 av = *(const bf16x8*)&Vs[buf][dr * 64 + ((cc * 32 + l4 * 8) ^ swz_rd)];
        o[d] = __builtin_amdgcn_mfma_f32_16x16x32_bf16(av, pa[cc], o[d], 0, 0, 0);
      }
    }
    __builtin_amdgcn_s_setprio(0);

    __syncthreads();
    buf ^= 1;
  }

  float lv = l_run;
  lv += __shfl_xor(lv, 16);
  lv += __shfl_xor(lv, 32);
  float inv = 1.f / lv;
  size_t rowbase = ((size_t)(b * SS + q0 + l15)) * DDIM + h * DEPTH;
#pragma unroll
  for (int d = 0; d < 4; d++) {
    *(uint*)&ctx[rowbase + d * 16 + l4 * 4]     = pkbf(o[d][0] * inv, o[d][1] * inv);
    *(uint*)&ctx[rowbase + d * 16 + l4 * 4 + 2] = pkbf(o[d][2] * inv, o[d][3] * inv);
  }
}

extern "C" void kernel_launch(void* const* d_in, const int* in_sizes, int n_in,
                              void* d_out, int out_size, void* d_ws, size_t ws_size,
                              hipStream_t stream) {
  const float* query = (const float*)d_in[0];
  const float* key_  = (const float*)d_in[1];
  const float* value = (const float*)d_in[2];
  const float* Wq = (const float*)d_in[4];
  const float* Wk = (const float*)d_in[5];
  const float* Wv = (const float*)d_in[6];
  const float* Wo = (const float*)d_in[7];
  const float* bq = (const float*)d_in[8];
  const float* bk = (const float*)d_in[9];
  const float* bv = (const float*)d_in[10];
  const float* bo = (const float*)d_in[11];

  char* ws = (char*)d_ws;
  const size_t MB = 1u << 20;
  ushort* Wqt = (ushort*)(ws + 24 * MB);
  ushort* Wkt = (ushort*)(ws + 26 * MB);
  ushort* Wvt = (ushort*)(ws + 28 * MB);
  ushort* Wot = (ushort*)(ws + 30 * MB);
  ushort* Qh  = (ushort*)(ws + 32 * MB);   // [bh][2048][64]
  ushort* Kh  = (ushort*)(ws + 40 * MB);   // [bh][2048][64]
  ushort* Vtg = (ushort*)(ws + 48 * MB);   // [bh][64][2048]
  ushort* Cb  = (ushort*)(ws + 56 * MB);   // [4096][1024]

  wprep_kernel<<<4096, 256, 0, stream>>>(Wq, Wk, Wv, Wo, Wqt, Wkt, Wvt, Wot);

  qkv_gemm_kernel<<<768, 256, 0, stream>>>(
      query, key_, value, Wqt, Wkt, Wvt, bq, bk, bv, Qh, Kh, Vtg);

  attn_kernel<<<1024, 256, 0, stream>>>(Qh, Kh, Vtg, Cb);

  out_gemm_kernel<<<512, 256, 0, stream>>>(
      Cb, Wot, bo, (float*)d_out, MROWS, DDIM, DDIM);
}

// Round 8
// 116.810 us; speedup vs baseline: 1.3254x; 1.0115x over previous
//
#include <hip/hip_runtime.h>
#include <hip/hip_bf16.h>
#include <stdint.h>

#define BB 2
#define SS 2048
#define DDIM 1024
#define HH 16
#define DEPTH 64
#define MROWS (BB*SS)   // 4096

typedef short bf16x8 __attribute__((ext_vector_type(8)));
typedef float f32x4 __attribute__((ext_vector_type(4)));

__device__ inline ushort f2bf(float f) {
  union { float f; unsigned u; } v; v.f = f;
  unsigned r = v.u + 0x7fffu + ((v.u >> 16) & 1u);
  return (ushort)(r >> 16);
}

// HW packed f32x2 -> bf16x2 (RTNE), low = a, high = b  [m214 T12]
__device__ inline uint pkbf(float a, float b) {
  uint r;
  asm("v_cvt_pk_bf16_f32 %0, %1, %2" : "=v"(r) : "v"(a), "v"(b));
  return r;
}

__device__ inline void gload_lds16(const void* g, void* l) {
  __builtin_amdgcn_global_load_lds(
      (const __attribute__((address_space(1))) unsigned*)g,
      (__attribute__((address_space(3))) unsigned*)l,
      16, 0, 0);
}

// ---------------- weight transpose + convert: T[n][k] = W[k][n] ----------------
__global__ void wprep_kernel(const float* __restrict__ W0, const float* __restrict__ W1,
                             const float* __restrict__ W2, const float* __restrict__ W3,
                             ushort* __restrict__ T0, ushort* __restrict__ T1,
                             ushort* __restrict__ T2, ushort* __restrict__ T3) {
  __shared__ float tile[32][33];
  int z = blockIdx.x >> 10;
  int rr = blockIdx.x & 1023;
  const float* W = (z == 0) ? W0 : (z == 1) ? W1 : (z == 2) ? W2 : W3;
  ushort* T = (z == 0) ? T0 : (z == 1) ? T1 : (z == 2) ? T2 : T3;
  int tx = threadIdx.x & 31, ty = threadIdx.x >> 5;   // 32 x 8
  int n0 = (rr & 31) * 32, k0 = (rr >> 5) * 32;
#pragma unroll
  for (int i = 0; i < 4; i++)
    tile[ty + i * 8][tx] = W[(size_t)(k0 + ty + i * 8) * DDIM + n0 + tx];
  __syncthreads();
#pragma unroll
  for (int i = 0; i < 4; i++)
    T[(size_t)(n0 + ty + i * 8) * DDIM + k0 + tx] = f2bf(tile[tx][ty + i * 8]);
}

// ---------------- fused Q/K/V projection GEMM, BK=64, pipelined 2-phase ----------
// A (fp32) reg-staged+cvt fused; B (bf16 W^T) gload_lds into dbuf Bs.
// All t+1 loads issued BEFORE MFMA(t) so latency hides under compute.
__global__ __launch_bounds__(256, 3) void qkv_gemm_kernel(
    const float* __restrict__ Aq, const float* __restrict__ Ak, const float* __restrict__ Av,
    const ushort* __restrict__ Wqt, const ushort* __restrict__ Wkt, const ushort* __restrict__ Wvt,
    const float* __restrict__ bqp, const float* __restrict__ bkp, const float* __restrict__ bvp,
    ushort* __restrict__ Qh, ushort* __restrict__ Kh, ushort* __restrict__ Vtg) {
  const int id = blockIdx.x;
  const int xcd = id & 7;
  const int rest = id >> 3;          // 0..95
  const int xblk = rest & 7;         // n-block 0..7
  const int slot = rest >> 3;        // 0..11
  const int g = xcd * 12 + slot;     // 0..95
  const int yblk = g & 31;           // m-panel 0..31
  const int z = g >> 5;              // tensor 0..2

  const float*  Ap = (z == 0) ? Aq  : (z == 1) ? Ak  : Av;
  const ushort* Bt = (z == 0) ? Wqt : (z == 1) ? Wkt : Wvt;
  const float* bias = (z == 0) ? bqp : (z == 1) ? bkp : bvp;

  __shared__ __align__(16) ushort As[128 * 64];        // 16 KB
  __shared__ __align__(16) ushort Bs[2][128 * 64];     // 32 KB
  const int tid = threadIdx.x;
  const int w = tid >> 6, lane = tid & 63;
  const int m0 = yblk * 128, n0 = xblk * 128;
  const int wr = (w >> 1) * 64, wc = (w & 1) * 64;
  const int l4 = lane >> 4, l15 = lane & 15;
  const int row16 = tid >> 4;          // 0..15
  const int col4 = (tid & 15) * 4;     // fp32/bf16 col within 64
  const int srow8 = w * 8 + (lane >> 3);
  const int scol8 = (lane & 7) * 8;

  f32x4 zero = {0.f, 0.f, 0.f, 0.f};
  f32x4 acc[4][4];
#pragma unroll
  for (int i = 0; i < 4; i++)
#pragma unroll
    for (int j = 0; j < 4; j++) acc[i][j] = zero;

  // ---- prologue: tile 0 ----
  float4 areg[8];
#pragma unroll
  for (int j = 0; j < 8; ++j)
    areg[j] = *(const float4*)&Ap[(size_t)(m0 + j * 16 + row16) * DDIM + col4];
#pragma unroll
  for (int it = 0; it < 4; ++it)
    gload_lds16(Bt + (size_t)(n0 + it * 32 + srow8) * DDIM + scol8,
                &Bs[0][(it * 32 + w * 8) * 64]);
#pragma unroll
  for (int j = 0; j < 8; ++j) {
    uint2 pk;
    pk.x = pkbf(areg[j].x, areg[j].y);
    pk.y = pkbf(areg[j].z, areg[j].w);
    *(uint2*)&As[(j * 16 + row16) * 64 + col4] = pk;
  }
  __syncthreads();

  int buf = 0;
  for (int t = 0; t < 16; ++t) {
    // ---- issue ALL t+1 loads before compute (latency hides under MFMA) ----
    if (t + 1 < 16) {
#pragma unroll
      for (int it = 0; it < 4; ++it)
        gload_lds16(Bt + (size_t)(n0 + it * 32 + srow8) * DDIM + (t + 1) * 64 + scol8,
                    &Bs[buf ^ 1][(it * 32 + w * 8) * 64]);
#pragma unroll
      for (int j = 0; j < 8; ++j)
        areg[j] = *(const float4*)&Ap[(size_t)(m0 + j * 16 + row16) * DDIM + (t + 1) * 64 + col4];
    }
    // ---- 32 MFMA on current tile ----
#pragma unroll
    for (int kk = 0; kk < 2; ++kk) {
      bf16x8 af[4], bfr[4];
#pragma unroll
      for (int m = 0; m < 4; m++)
        af[m] = *(const bf16x8*)&As[(wr + m * 16 + l15) * 64 + kk * 32 + l4 * 8];
#pragma unroll
      for (int n = 0; n < 4; n++)
        bfr[n] = *(const bf16x8*)&Bs[buf][(wc + n * 16 + l15) * 64 + kk * 32 + l4 * 8];
#pragma unroll
      for (int m = 0; m < 4; m++)
#pragma unroll
        for (int n = 0; n < 4; n++)
          acc[m][n] = __builtin_amdgcn_mfma_f32_16x16x32_bf16(af[m], bfr[n], acc[m][n], 0, 0, 0);
    }
    __syncthreads();            // all waves done reading As
    if (t + 1 < 16) {
#pragma unroll
      for (int j = 0; j < 8; ++j) {
        uint2 pk;
        pk.x = pkbf(areg[j].x, areg[j].y);
        pk.y = pkbf(areg[j].z, areg[j].w);
        *(uint2*)&As[(j * 16 + row16) * 64 + col4] = pk;
      }
    }
    __syncthreads();            // A visible; B(t+1) DMA drained
    buf ^= 1;
  }

  if (z != 2) {
    // Q/K epilogue: wave-private 64x64 LDS bounce (XOR-swizzled) -> coalesced 16B stores
    ushort* outp = (z == 0) ? Qh : Kh;
    ushort* wtile = (w < 2) ? &As[w * 4096] : &Bs[0][(w - 2) * 4096];
    const int gcol0 = n0 + wc;          // 64-aligned -> one head per wave
    const int hh = gcol0 >> 6;
    const int bb = m0 >> 11;
    const int s0g = (m0 + wr) & (SS - 1);
#pragma unroll
    for (int m = 0; m < 4; m++) {
#pragma unroll
      for (int n = 0; n < 4; n++) {
        int dloc = n * 16 + l15;
        float bv = bias[gcol0 + dloc];
#pragma unroll
        for (int r = 0; r < 4; r++) {
          int sloc = m * 16 + l4 * 4 + r;
          wtile[sloc * 64 + (dloc ^ ((sloc & 7) << 3))] = f2bf(acc[m][n][r] + bv);
        }
      }
    }
#pragma unroll
    for (int i = 0; i < 8; ++i) {
      int srow = i * 8 + (lane >> 3);
      int dch = (lane & 7) * 8;
      bf16x8 val = *(const bf16x8*)&wtile[srow * 64 + (dch ^ ((srow & 7) << 3))];
      *(bf16x8*)&outp[((size_t)(bb * HH + hh) * SS + s0g + srow) * DEPTH + dch] = val;
    }
  } else {
    // V^T epilogue: per-wave LDS-bounce transpose -> coalesced 16B stores
    ushort* wtile = (w < 2) ? &As[w * 2048] : &Bs[0][(w - 2) * 2048];  // 32 d x 64 s
    const int gcol0 = n0 + wc;
    const int hh = gcol0 >> 6;
    const int bb = m0 >> 11;
    const int s0g = (m0 + wr) & (SS - 1);
#pragma unroll
    for (int p = 0; p < 2; ++p) {
#pragma unroll
      for (int nn = 0; nn < 2; ++nn) {
        int n = p * 2 + nn;
        int dloc = nn * 16 + l15;
        float bv = bias[gcol0 + p * 32 + dloc];
#pragma unroll
        for (int m = 0; m < 4; m++) {
#pragma unroll
          for (int rr = 0; rr < 4; rr += 2) {
            int sloc = m * 16 + l4 * 4 + rr;
            int gg = (sloc >> 3) ^ (dloc & 7);
            uint pk = pkbf(acc[m][n][rr] + bv, acc[m][n][rr + 1] + bv);
            *(uint*)&wtile[dloc * 64 + gg * 8 + (sloc & 7)] = pk;
          }
        }
      }
      __syncthreads();
#pragma unroll
      for (int i = 0; i < 4; ++i) {
        int dloc = (lane >> 3) + i * 8;
        int gg = (lane & 7) ^ (dloc & 7);
        bf16x8 val = *(const bf16x8*)&wtile[dloc * 64 + gg * 8];
        int dglob = p * 32 + dloc;
        size_t addr = ((size_t)(bb * HH + hh) * DEPTH + dglob) * SS + s0g + (lane & 7) * 8;
        *(bf16x8*)&Vtg[addr] = val;
      }
      __syncthreads();
    }
  }
}

// ---------------- output GEMM: 128x64 tile, BK=64, full dbuf, 1 barrier/iter -----
__global__ __launch_bounds__(256, 3) void out_gemm_kernel(
    const ushort* __restrict__ A, const ushort* __restrict__ Bt,
    const float* __restrict__ bias, float* __restrict__ out,
    int M, int N, int K) {
  __shared__ __align__(16) ushort As[2][128 * 64];   // 32 KB
  __shared__ __align__(16) ushort Bs[2][64 * 64];    // 16 KB
  const int id = blockIdx.x;
  const int xcd = id & 7;
  const int rest = id >> 3;          // 0..63
  const int xblk = rest & 15;        // n-block 0..15
  const int slot = rest >> 4;        // 0..3
  const int yblk = xcd * 4 + slot;   // m-panel 0..31

  const int tid = threadIdx.x;
  const int w = tid >> 6, lane = tid & 63;
  const int m0 = yblk * 128, n0 = xblk * 64;
  const int wr = (w >> 1) * 64, wc = (w & 1) * 32;
  const int l4 = lane >> 4, l15 = lane & 15;
  const int srow8 = w * 8 + (lane >> 3);
  const int scol8 = (lane & 7) * 8;

  f32x4 zero = {0.f, 0.f, 0.f, 0.f};
  f32x4 acc[4][2];
#pragma unroll
  for (int i = 0; i < 4; i++)
#pragma unroll
    for (int j = 0; j < 2; j++) acc[i][j] = zero;

  // prologue: stage tile 0
#pragma unroll
  for (int it = 0; it < 4; ++it)
    gload_lds16(A + (size_t)(m0 + it * 32 + srow8) * K + scol8,
                &As[0][(it * 32 + w * 8) * 64]);
#pragma unroll
  for (int it = 0; it < 2; ++it)
    gload_lds16(Bt + (size_t)(n0 + it * 32 + srow8) * K + scol8,
                &Bs[0][(it * 32 + w * 8) * 64]);
  __syncthreads();

  int buf = 0;
  for (int t = 0; t < 16; ++t) {
    if (t + 1 < 16) {
#pragma unroll
      for (int it = 0; it < 4; ++it)
        gload_lds16(A + (size_t)(m0 + it * 32 + srow8) * K + (t + 1) * 64 + scol8,
                    &As[buf ^ 1][(it * 32 + w * 8) * 64]);
#pragma unroll
      for (int it = 0; it < 2; ++it)
        gload_lds16(Bt + (size_t)(n0 + it * 32 + srow8) * K + (t + 1) * 64 + scol8,
                    &Bs[buf ^ 1][(it * 32 + w * 8) * 64]);
    }
#pragma unroll
    for (int kk = 0; kk < 2; ++kk) {
      bf16x8 af[4], bfr[2];
#pragma unroll
      for (int m = 0; m < 4; m++)
        af[m] = *(const bf16x8*)&As[buf][(wr + m * 16 + l15) * 64 + kk * 32 + l4 * 8];
#pragma unroll
      for (int n = 0; n < 2; n++)
        bfr[n] = *(const bf16x8*)&Bs[buf][(wc + n * 16 + l15) * 64 + kk * 32 + l4 * 8];
#pragma unroll
      for (int m = 0; m < 4; m++)
#pragma unroll
        for (int n = 0; n < 2; n++)
          acc[m][n] = __builtin_amdgcn_mfma_f32_16x16x32_bf16(af[m], bfr[n], acc[m][n], 0, 0, 0);
    }
    __syncthreads();
    buf ^= 1;
  }

#pragma unroll
  for (int m = 0; m < 4; m++) {
#pragma unroll
    for (int n = 0; n < 2; n++) {
      int col = n0 + wc + n * 16 + l15;
      float bv = bias[col];
#pragma unroll
      for (int r = 0; r < 4; r++) {
        int row = m0 + wr + m * 16 + l4 * 4 + r;
        out[(size_t)row * N + col] = acc[m][n][r] + bv;
      }
    }
  }
}

// ---------------- causal flash attention: 1024 LPT-ordered blocks, 4/CU ---------
__global__ __launch_bounds__(256, 4) void attn_kernel(
    const ushort* __restrict__ Qh, const ushort* __restrict__ Kh,
    const ushort* __restrict__ Vt, ushort* __restrict__ ctx) {
  __shared__ __align__(16) ushort Ks[2][64 * 64];   // [kv][d], XOR-swizzled
  __shared__ __align__(16) ushort Vs[2][64 * 64];   // [d][kv], XOR-swizzled
  __shared__ __align__(16) ushort Ps[4][16 * 64];   // per-wave P, XOR-swizzled
  const int tid = threadIdx.x;
  const int w = tid >> 6, lane = tid & 63;
  const int l4 = lane >> 4, l15 = lane & 15;
  const float CE = 0.18033688f;                     // 0.125 * log2(e)

  const int xcd = blockIdx.x & 7;
  const int local = blockIdx.x >> 3;                // 0..127
  const int bh = xcd * 4 + (local & 3);
  const int chunk = 31 - (local >> 2);
  const int b = bh >> 4, h = bh & 15;
  const size_t qkbase = (size_t)bh * SS * DEPTH;
  const size_t vbase  = (size_t)bh * DEPTH * SS;

  const int srow_w = w * 8 + (lane >> 3);
  const int colb_lin = (lane & 7) * 16;
  const int swz_rd = (l15 & 7) << 3;

  const int q0 = chunk * 64 + w * 16;
  const int nt = chunk + 1;

  bf16x8 aq[2];
#pragma unroll
  for (int cc = 0; cc < 2; cc++)
    aq[cc] = *(const bf16x8*)&Qh[qkbase + (size_t)(q0 + l15) * DEPTH + cc * 32 + l4 * 8];

  f32x4 zero = {0.f, 0.f, 0.f, 0.f};
  f32x4 o[4];
  float m_run = -__builtin_inff(), l_run = 0.f;
#pragma unroll
  for (int d = 0; d < 4; d++) o[d] = zero;

  int buf = 0;
#pragma unroll
  for (int it = 0; it < 2; ++it) {
    int row = it * 32 + srow_w;
    int col_e = (colb_lin ^ ((row & 7) << 4)) >> 1;
    int ldsoff = it * 2048 + w * 512;
    gload_lds16(Kh + qkbase + (size_t)row * DEPTH + col_e, &Ks[0][ldsoff]);
    gload_lds16(Vt + vbase + (size_t)row * SS + col_e, &Vs[0][ldsoff]);
  }
  __syncthreads();

  for (int t = 0; t < nt; ++t) {
    if (t + 1 < nt) {
      const int kv1 = (t + 1) * 64;
#pragma unroll
      for (int it = 0; it < 2; ++it) {
        int row = it * 32 + srow_w;
        int col_e = (colb_lin ^ ((row & 7) << 4)) >> 1;
        int ldsoff = it * 2048 + w * 512;
        gload_lds16(Kh + qkbase + (size_t)(kv1 + row) * DEPTH + col_e, &Ks[buf ^ 1][ldsoff]);
        gload_lds16(Vt + vbase + (size_t)row * SS + kv1 + col_e, &Vs[buf ^ 1][ldsoff]);
      }
    }

    const int kv0 = t * 64;
    f32x4 s[4];
    __builtin_amdgcn_s_setprio(1);
#pragma unroll
    for (int n = 0; n < 4; n++) {
      f32x4 zacc = zero;
      int kr = n * 16 + l15;
#pragma unroll
      for (int cc = 0; cc < 2; cc++) {
        bf16x8 bk = *(const bf16x8*)&Ks[buf][kr * 64 + ((cc * 32 + l4 * 8) ^ swz_rd)];
        zacc = __builtin_amdgcn_mfma_f32_16x16x32_bf16(bk, aq[cc], zacc, 0, 0, 0);
      }
      s[n] = zacc;
    }
    __builtin_amdgcn_s_setprio(0);

    const int qg = q0 + l15;
    if (t == nt - 1) {
#pragma unroll
      for (int n = 0; n < 4; n++) {
        int kb = kv0 + n * 16 + l4 * 4;
#pragma unroll
        for (int r = 0; r < 4; r++)
          if (kb + r > qg) s[n][r] = -1e9f;
      }
    }

    float mx = -__builtin_inff();
#pragma unroll
    for (int n = 0; n < 4; n++)
      mx = fmaxf(mx, fmaxf(fmaxf(s[n][0], s[n][1]), fmaxf(s[n][2], s[n][3])));
    mx = fmaxf(mx, __shfl_xor(mx, 16));
    mx = fmaxf(mx, __shfl_xor(mx, 32));
    if (!__all(mx - m_run <= 44.36f)) {      // defer-max: P bounded by 2^8
      float mnew = fmaxf(m_run, mx);
      float alpha = exp2f((m_run - mnew) * CE);
      m_run = mnew;
      l_run *= alpha;
#pragma unroll
      for (int d = 0; d < 4; d++) o[d] *= alpha;
    }
    float mc = m_run * CE;
    float rs = 0.f;
#pragma unroll
    for (int n = 0; n < 4; n++)
#pragma unroll
      for (int r = 0; r < 4; r++) {
        float p = exp2f(s[n][r] * CE - mc);
        s[n][r] = p;
        rs += p;
      }
    l_run += rs;

    ushort* Pw = &Ps[w][0];
#pragma unroll
    for (int n = 0; n < 4; n++) {
      int col = (n * 16 + l4 * 4) ^ swz_rd;
      uint2 pk;
      pk.x = pkbf(s[n][0], s[n][1]);
      pk.y = pkbf(s[n][2], s[n][3]);
      *(uint2*)&Pw[l15 * 64 + col] = pk;
    }

    bf16x8 pa[2];
#pragma unroll
    for (int cc = 0; cc < 2; cc++)
      pa[cc] = *(const bf16x8*)&Pw[l15 * 64 + ((cc * 32 + l4 * 8) ^ swz_rd)];

    __builtin_amdgcn_s_setprio(1);
#pragma unroll
    for (int d = 0; d < 4; d++) {
      int dr = d * 16 + l15;
#pragma unroll
      for (int cc = 0; cc < 2; cc++) {
        bf16x8 av = *(const bf16x8*)&Vs[buf][dr * 64 + ((cc * 32 + l4 * 8) ^ swz_rd)];
        o[d] = __builtin_amdgcn_mfma_f32_16x16x32_bf16(av, pa[cc], o[d], 0, 0, 0);
      }
    }
    __builtin_amdgcn_s_setprio(0);

    __syncthreads();
    buf ^= 1;
  }

  float lv = l_run;
  lv += __shfl_xor(lv, 16);
  lv += __shfl_xor(lv, 32);
  float inv = 1.f / lv;
  size_t rowbase = ((size_t)(b * SS + q0 + l15)) * DDIM + h * DEPTH;
#pragma unroll
  for (int d = 0; d < 4; d++) {
    *(uint*)&ctx[rowbase + d * 16 + l4 * 4]     = pkbf(o[d][0] * inv, o[d][1] * inv);
    *(uint*)&ctx[rowbase + d * 16 + l4 * 4 + 2] = pkbf(o[d][2] * inv, o[d][3] * inv);
  }
}

extern "C" void kernel_launch(void* const* d_in, const int* in_sizes, int n_in,
                              void* d_out, int out_size, void* d_ws, size_t ws_size,
                              hipStream_t stream) {
  const float* query = (const float*)d_in[0];
  const float* key_  = (const float*)d_in[1];
  const float* value = (const float*)d_in[2];
  const float* Wq = (const float*)d_in[4];
  const float* Wk = (const float*)d_in[5];
  const float* Wv = (const float*)d_in[6];
  const float* Wo = (const float*)d_in[7];
  const float* bq = (const float*)d_in[8];
  const float* bk = (const float*)d_in[9];
  const float* bv = (const float*)d_in[10];
  const float* bo = (const float*)d_in[11];

  char* ws = (char*)d_ws;
  const size_t MB = 1u << 20;
  ushort* Wqt = (ushort*)(ws + 24 * MB);
  ushort* Wkt = (ushort*)(ws + 26 * MB);
  ushort* Wvt = (ushort*)(ws + 28 * MB);
  ushort* Wot = (ushort*)(ws + 30 * MB);
  ushort* Qh  = (ushort*)(ws + 32 * MB);   // [bh][2048][64]
  ushort* Kh  = (ushort*)(ws + 40 * MB);   // [bh][2048][64]
  ushort* Vtg = (ushort*)(ws + 48 * MB);   // [bh][64][2048]
  ushort* Cb  = (ushort*)(ws + 56 * MB);   // [4096][1024]

  wprep_kernel<<<4096, 256, 0, stream>>>(Wq, Wk, Wv, Wo, Wqt, Wkt, Wvt, Wot);

  qkv_gemm_kernel<<<768, 256, 0, stream>>>(
      query, key_, value, Wqt, Wkt, Wvt, bq, bk, bv, Qh, Kh, Vtg);

  attn_kernel<<<1024, 256, 0, stream>>>(Qh, Kh, Vtg, Cb);

  out_gemm_kernel<<<512, 256, 0, stream>>>(
      Cb, Wot, bo, (float*)d_out, MROWS, DDIM, DDIM);
}